// Round 2
// baseline (5776.966 us; speedup 1.0000x reference)
//
#include <hip/hip_runtime.h>
#include <cstdint>
#include <cstddef>

#define GG 64

typedef unsigned int uint;
typedef unsigned short ushort;

// ---------------- preprocessing ----------------

__global__ __launch_bounds__(256) void count_kernel(const int* __restrict__ col,
                                                    int* __restrict__ cnt, int E) {
  int e = blockIdx.x * blockDim.x + threadIdx.x;
  if (e < E) atomicAdd(&cnt[col[e]], 1);
}

__global__ __launch_bounds__(256) void scan_block_sums(const int* __restrict__ cnt,
                                                       int* __restrict__ bsums,
                                                       int n, int cpt) {
  __shared__ int sdata[256];
  const int tid = threadIdx.x;
  const int base = (blockIdx.x * 256 + tid) * cpt;
  int s = 0;
  for (int j = 0; j < cpt; ++j) {
    int i = base + j;
    if (i < n) s += cnt[i];
  }
  sdata[tid] = s;
  __syncthreads();
  for (int off = 128; off > 0; off >>= 1) {
    if (tid < off) sdata[tid] += sdata[tid + off];
    __syncthreads();
  }
  if (tid == 0) bsums[blockIdx.x] = sdata[0];
}

__global__ void scan_offsets(int* __restrict__ bsums) {
  if (threadIdx.x == 0 && blockIdx.x == 0) {
    int run = 0;
    for (int b = 0; b < 256; ++b) {
      int v = bsums[b];
      bsums[b] = run;
      run += v;
    }
  }
}

__global__ __launch_bounds__(256) void scan_write(const int* __restrict__ cnt,
                                                  const int* __restrict__ boff,
                                                  int* __restrict__ indptr,
                                                  int* __restrict__ cursor,
                                                  float* __restrict__ dis,
                                                  int n, int cpt, int total) {
  __shared__ int sdata[256];
  const int tid = threadIdx.x;
  const int base = (blockIdx.x * 256 + tid) * cpt;
  int s = 0;
  for (int j = 0; j < cpt; ++j) {
    int i = base + j;
    if (i < n) s += cnt[i];
  }
  sdata[tid] = s;
  __syncthreads();
  for (int off = 1; off < 256; off <<= 1) {
    int v = 0;
    if (tid >= off) v = sdata[tid - off];
    __syncthreads();
    sdata[tid] += v;
    __syncthreads();
  }
  int run = boff[blockIdx.x] + sdata[tid] - s;  // exclusive prefix
  for (int j = 0; j < cpt; ++j) {
    int i = base + j;
    if (i < n) {
      indptr[i] = run;
      cursor[i] = run;
      int cv = cnt[i];
      dis[i] = rsqrtf((float)(cv + 1));  // +1 self loop, deg >= 1 always
      run += cv;
    }
  }
  if (blockIdx.x == 0 && tid == 0) indptr[n] = total;
}

__global__ __launch_bounds__(256) void fill_kernel(const int* __restrict__ row,
                                                   const int* __restrict__ col,
                                                   int* __restrict__ cursor,
                                                   int* __restrict__ csr, int E) {
  int e = blockIdx.x * blockDim.x + threadIdx.x;
  if (e < E) {
    int pos = atomicAdd(&cursor[col[e]], 1);
    csr[pos] = row[e];
  }
}

// ---------------- GEMM: Cb[r][:] = bf16( (A[r,:] @ W) * scale[r] ) ----------------
// BM=128 rows/block, BK=32 double-buffered, 256 threads, 8x8 micro-tile.
// As swizzled (conflict-free), Ws transposed+swizzled (2-way, free).

#define BM 128
#define BK 32

__device__ __forceinline__ uint bf16rne(float f) {
  uint u = __float_as_uint(f);
  return (u + 0x7fffu + ((u >> 16) & 1u)) >> 16;
}

__global__ __launch_bounds__(256) void gemm128(const float* __restrict__ A,
                                               const float* __restrict__ W,
                                               const float* __restrict__ scale,
                                               uint* __restrict__ Cb, int n) {
  __shared__ float As[2][BM * BK];   // word = r*32 + (k ^ (((r>>3)&3)<<2))
  __shared__ float Ws[2][128 * BK];  // transposed: word = c*32 + (k ^ (((c>>3)&7)<<2))
  const int tid = threadIdx.x;
  const int row0 = blockIdx.x * BM;

  auto stageA = [&](int buf, int k0) {
#pragma unroll
    for (int p = 0; p < 4; ++p) {
      int idx = p * 256 + tid;       // 1024 float4 loads = 128x32 floats
      int r = idx >> 3;
      int c4 = (idx & 7) << 2;
      int ar = row0 + r;
      float4 v = make_float4(0.f, 0.f, 0.f, 0.f);
      if (ar < n) v = *reinterpret_cast<const float4*>(A + (size_t)ar * 128 + k0 + c4);
      int sw = ((r >> 3) & 3) << 2;
      *reinterpret_cast<float4*>(&As[buf][r * 32 + (c4 ^ sw)]) = v;
    }
  };
  auto stageW = [&](int buf, int k0) {
#pragma unroll
    for (int p = 0; p < 4; ++p) {
      int idx = p * 256 + tid;       // 1024 float4 loads = 32x128 floats
      int k = idx >> 5;
      int c4 = (idx & 31) << 2;
      float4 v = *reinterpret_cast<const float4*>(W + (size_t)(k0 + k) * 128 + c4);
#pragma unroll
      for (int j = 0; j < 4; ++j) {
        int c = c4 + j;
        int sw = ((c >> 3) & 7) << 2;
        Ws[buf][c * 32 + (k ^ sw)] = (&v.x)[j];
      }
    }
  };

  stageA(0, 0);
  stageW(0, 0);
  __syncthreads();

  const int ty = tid >> 4, tx = tid & 15;
  const int r0 = ty << 3, c0 = tx << 3;
  const int swA = (ty & 3) << 2;
  const int swW = (tx & 7) << 2;

  float acc[8][8];
#pragma unroll
  for (int i = 0; i < 8; ++i)
#pragma unroll
    for (int j = 0; j < 8; ++j) acc[i][j] = 0.f;

#pragma unroll
  for (int ks = 0; ks < 4; ++ks) {
    const int buf = ks & 1;
    if (ks < 3) {
      stageA(buf ^ 1, (ks + 1) * BK);
      stageW(buf ^ 1, (ks + 1) * BK);
    }
    const float* Ap = &As[buf][0];
    const float* Wp = &Ws[buf][0];
#pragma unroll
    for (int k4 = 0; k4 < BK; k4 += 4) {
      float4 a[8], w[8];
#pragma unroll
      for (int i = 0; i < 8; ++i)
        a[i] = *reinterpret_cast<const float4*>(Ap + (r0 + i) * 32 + (k4 ^ swA));
#pragma unroll
      for (int j = 0; j < 8; ++j)
        w[j] = *reinterpret_cast<const float4*>(Wp + (c0 + j) * 32 + (k4 ^ swW));
#pragma unroll
      for (int kk = 0; kk < 4; ++kk)
#pragma unroll
        for (int i = 0; i < 8; ++i)
#pragma unroll
          for (int j = 0; j < 8; ++j)
            acc[i][j] = fmaf((&a[i].x)[kk], (&w[j].x)[kk], acc[i][j]);
    }
    __syncthreads();
  }

#pragma unroll
  for (int i = 0; i < 8; ++i) {
    int rr = row0 + r0 + i;
    if (rr < n) {
      float s = scale[rr];
      uint4 o;
      o.x = bf16rne(acc[i][0] * s) | (bf16rne(acc[i][1] * s) << 16);
      o.y = bf16rne(acc[i][2] * s) | (bf16rne(acc[i][3] * s) << 16);
      o.z = bf16rne(acc[i][4] * s) | (bf16rne(acc[i][5] * s) << 16);
      o.w = bf16rne(acc[i][6] * s) | (bf16rne(acc[i][7] * s) << 16);
      *reinterpret_cast<uint4*>(Cb + (size_t)rr * 64 + (c0 >> 1)) = o;
    }
  }
}

// ---------------- aggregation ----------------
// O[i] = relu( dis[i]*( sum_{e:col=i} T'[src] + T'[i] ) + b ),  T' bf16-packed

__global__ __launch_bounds__(256) void agg_kernel(const uint* __restrict__ T,
                                                  const int* __restrict__ indptr,
                                                  const int* __restrict__ csr,
                                                  const float* __restrict__ dis,
                                                  const float* __restrict__ bias,
                                                  float* __restrict__ O, int n) {
  int wid = (blockIdx.x << 2) + (threadIdx.x >> 6);  // one wave per node
  if (wid >= n) return;
  wid = __builtin_amdgcn_readfirstlane(wid);
  const int lane = threadIdx.x & 63;
  const int e0 = indptr[wid], e1 = indptr[wid + 1];
  float ax = 0.f, ay = 0.f;
#define TLOAD(s) T[(size_t)(s) * 64 + lane]
#define BLO(u) __uint_as_float((u) << 16)
#define BHI(u) __uint_as_float((u) & 0xffff0000u)
  int e = e0;
  for (; e + 4 <= e1; e += 4) {
    int s0 = csr[e], s1 = csr[e + 1], s2 = csr[e + 2], s3 = csr[e + 3];
    uint u0 = TLOAD(s0);
    uint u1 = TLOAD(s1);
    uint u2 = TLOAD(s2);
    uint u3 = TLOAD(s3);
    ax += (BLO(u0) + BLO(u1)) + (BLO(u2) + BLO(u3));
    ay += (BHI(u0) + BHI(u1)) + (BHI(u2) + BHI(u3));
  }
  for (; e < e1; ++e) {
    uint u = TLOAD(csr[e]);
    ax += BLO(u);
    ay += BHI(u);
  }
  uint us = TLOAD(wid);  // self loop
  ax += BLO(us);
  ay += BHI(us);
  const float di = dis[wid];
  const float2 b = *reinterpret_cast<const float2*>(bias + lane * 2);
  float ox = fmaxf(fmaf(di, ax, b.x), 0.f);
  float oy = fmaxf(fmaf(di, ay, b.y), 0.f);
  *reinterpret_cast<float2*>(O + (size_t)wid * 128 + lane * 2) = make_float2(ox, oy);
}

// ---------------- pooling over sorted batch ids ----------------

__global__ __launch_bounds__(256) void pool_kernel(const float* __restrict__ H,
                                                   const int* __restrict__ batch,
                                                   float* __restrict__ pooled,
                                                   float* __restrict__ cntg, int n) {
  const int tid = threadIdx.x;
  const int c = tid & 127;
  const int half = tid >> 7;
  const int base = blockIdx.x * 256;
  float acc = 0.f;
  int cnt = 0;
  int curg = -1;
  for (int rr = half; rr < 256; rr += 2) {
    int rowi = base + rr;
    if (rowi >= n) break;
    int g = batch[rowi];
    if (g != curg) {
      if (curg >= 0) {
        atomicAdd(&pooled[curg * 128 + c], acc);
        if (c == 0) atomicAdd(&cntg[curg], (float)cnt);
      }
      curg = g;
      acc = 0.f;
      cnt = 0;
    }
    acc += H[(size_t)rowi * 128 + c];
    cnt++;
  }
  if (curg >= 0) {
    atomicAdd(&pooled[curg * 128 + c], acc);
    if (c == 0) atomicAdd(&cntg[curg], (float)cnt);
  }
}

__global__ __launch_bounds__(128) void final_kernel(const float* __restrict__ pooled,
                                                    const float* __restrict__ cntg,
                                                    const float* __restrict__ Wp,
                                                    const float* __restrict__ bp,
                                                    float* __restrict__ out) {
  const int g = blockIdx.x;
  const int e = threadIdx.x;
  float inv = 1.0f / fmaxf(cntg[g], 1.0f);
  float acc = 0.f;
  for (int c = 0; c < 128; ++c)
    acc = fmaf(pooled[g * 128 + c], Wp[c * 128 + e], acc);
  out[g * 128 + e] = acc * inv + bp[e];
}

// ---------------- launch ----------------

extern "C" void kernel_launch(void* const* d_in, const int* in_sizes, int n_in,
                              void* d_out, int out_size, void* d_ws, size_t ws_size,
                              hipStream_t stream) {
  const float* x = (const float*)d_in[0];
  const int* eidx = (const int*)d_in[1];
  const int* batch = (const int*)d_in[2];
  const float* W1 = (const float*)d_in[3];
  const float* b1 = (const float*)d_in[4];
  const float* W2 = (const float*)d_in[5];
  const float* b2 = (const float*)d_in[6];
  const float* Wp = (const float*)d_in[7];
  const float* bp = (const float*)d_in[8];

  const int n = in_sizes[0] / 128;
  const int E = in_sizes[1] / 2;
  const int* row = eidx;      // edge_index[0] = sources
  const int* col = eidx + E;  // edge_index[1] = targets

  char* ws = (char*)d_ws;
  size_t off = 0;
  auto alloc = [&](size_t bytes) {
    void* p = ws + off;
    off = (off + bytes + 255) & ~(size_t)255;
    return p;
  };
  uint* Tb = (uint*)alloc((size_t)n * 64 * 4);     // bf16-packed messages (shared L1/L2)
  float* B = (float*)alloc((size_t)n * 128 * 4);   // agg output (shared L1/L2)
  float* dis = (float*)alloc((size_t)n * 4);
  int* indptr = (int*)alloc((size_t)(n + 1) * 4);
  int* cnt_i = (int*)alloc((size_t)n * 4);
  int* cursor = (int*)alloc((size_t)n * 4);
  int* csr = (int*)alloc((size_t)E * 4);
  float* pooled = (float*)alloc((size_t)GG * 128 * 4);
  float* cntg = (float*)alloc((size_t)GG * 4);
  int* bsums = (int*)alloc(256 * 4);
  (void)off;

  hipMemsetAsync(cnt_i, 0, (size_t)n * 4, stream);
  hipMemsetAsync(pooled, 0, (size_t)GG * 128 * 4, stream);
  hipMemsetAsync(cntg, 0, (size_t)GG * 4, stream);

  count_kernel<<<(E + 255) / 256, 256, 0, stream>>>(col, cnt_i, E);
  const int cpt = (n + 65535) / 65536;
  scan_block_sums<<<256, 256, 0, stream>>>(cnt_i, bsums, n, cpt);
  scan_offsets<<<1, 64, 0, stream>>>(bsums);
  scan_write<<<256, 256, 0, stream>>>(cnt_i, bsums, indptr, cursor, dis, n, cpt, E);
  fill_kernel<<<(E + 255) / 256, 256, 0, stream>>>(row, col, cursor, csr, E);

  const int gblocks = (n + BM - 1) / BM;
  gemm128<<<gblocks, 256, 0, stream>>>(x, W1, dis, Tb, n);      // T1' = (x@W1)*dis, bf16
  agg_kernel<<<(n + 3) / 4, 256, 0, stream>>>(Tb, indptr, csr, dis, b1, B, n);
  gemm128<<<gblocks, 256, 0, stream>>>(B, W2, dis, Tb, n);      // T2' = (B@W2)*dis, bf16
  agg_kernel<<<(n + 3) / 4, 256, 0, stream>>>(Tb, indptr, csr, dis, b2, B, n);

  pool_kernel<<<(n + 255) / 256, 256, 0, stream>>>(B, batch, pooled, cntg, n);
  final_kernel<<<GG, 128, 0, stream>>>(pooled, cntg, Wp, bp, (float*)d_out);
}

// Round 3
// 486.163 us; speedup vs baseline: 11.8828x; 11.8828x over previous
//
#include <hip/hip_runtime.h>
#include <cstdint>
#include <cstddef>

#define GG 64

typedef unsigned int uint;
typedef unsigned short ushort;
typedef __attribute__((ext_vector_type(8))) short short8v;  // 8 bf16 (4 VGPRs)
typedef __attribute__((ext_vector_type(4))) float f32x4;

// ---------------- preprocessing ----------------

__global__ __launch_bounds__(256) void count_kernel(const int* __restrict__ col,
                                                    int* __restrict__ cnt, int E) {
  int e = blockIdx.x * blockDim.x + threadIdx.x;
  if (e < E) atomicAdd(&cnt[col[e]], 1);
}

__global__ __launch_bounds__(256) void scan_block_sums(const int* __restrict__ cnt,
                                                       int* __restrict__ bsums,
                                                       int n, int cpt) {
  __shared__ int sdata[256];
  const int tid = threadIdx.x;
  const int base = (blockIdx.x * 256 + tid) * cpt;
  int s = 0;
  for (int j = 0; j < cpt; ++j) {
    int i = base + j;
    if (i < n) s += cnt[i];
  }
  sdata[tid] = s;
  __syncthreads();
  for (int off = 128; off > 0; off >>= 1) {
    if (tid < off) sdata[tid] += sdata[tid + off];
    __syncthreads();
  }
  if (tid == 0) bsums[blockIdx.x] = sdata[0];
}

__global__ void scan_offsets(int* __restrict__ bsums) {
  if (threadIdx.x == 0 && blockIdx.x == 0) {
    int run = 0;
    for (int b = 0; b < 256; ++b) {
      int v = bsums[b];
      bsums[b] = run;
      run += v;
    }
  }
}

__global__ __launch_bounds__(256) void scan_write(const int* __restrict__ cnt,
                                                  const int* __restrict__ boff,
                                                  int* __restrict__ indptr,
                                                  int* __restrict__ cursor,
                                                  float* __restrict__ dis,
                                                  int n, int cpt, int total) {
  __shared__ int sdata[256];
  const int tid = threadIdx.x;
  const int base = (blockIdx.x * 256 + tid) * cpt;
  int s = 0;
  for (int j = 0; j < cpt; ++j) {
    int i = base + j;
    if (i < n) s += cnt[i];
  }
  sdata[tid] = s;
  __syncthreads();
  for (int off = 1; off < 256; off <<= 1) {
    int v = 0;
    if (tid >= off) v = sdata[tid - off];
    __syncthreads();
    sdata[tid] += v;
    __syncthreads();
  }
  int run = boff[blockIdx.x] + sdata[tid] - s;  // exclusive prefix
  for (int j = 0; j < cpt; ++j) {
    int i = base + j;
    if (i < n) {
      indptr[i] = run;
      cursor[i] = run;
      int cv = cnt[i];
      dis[i] = rsqrtf((float)(cv + 1));  // +1 self loop, deg >= 1 always
      run += cv;
    }
  }
  if (blockIdx.x == 0 && tid == 0) indptr[n] = total;
}

__global__ __launch_bounds__(256) void fill_kernel(const int* __restrict__ row,
                                                   const int* __restrict__ col,
                                                   int* __restrict__ cursor,
                                                   int* __restrict__ csr, int E) {
  int e = blockIdx.x * blockDim.x + threadIdx.x;
  if (e < E) {
    int pos = atomicAdd(&cursor[col[e]], 1);
    csr[pos] = row[e];
  }
}

// ---------------- bf16 split helpers ----------------

__device__ __forceinline__ uint bf16rne(float f) {
  uint u = __float_as_uint(f);
  return (u + 0x7fffu + ((u >> 16) & 1u)) >> 16;
}

// Preconvert W [128][128] f32 into fragment-ready hi/lo bf16 buffers.
// Fragment slot (kc,j,lane) holds 8 bf16: W[kc*32 + (lane>>4)*8 + i][j*16 + (lane&15)]
// stored contiguously at (slot*8), slot = (kc*8+j)*64 + lane.  (2048 slots)
__global__ __launch_bounds__(256) void wconv_kernel(const float* __restrict__ W,
                                                    ushort* __restrict__ Whi,
                                                    ushort* __restrict__ Wlo) {
  int slot = blockIdx.x * 256 + threadIdx.x;
  if (slot >= 2048) return;
  int lane = slot & 63;
  int j = (slot >> 6) & 7;
  int kc = slot >> 9;
  ushort hb[8], lb[8];
#pragma unroll
  for (int i = 0; i < 8; ++i) {
    int k = kc * 32 + ((lane >> 4) << 3) + i;
    int c = j * 16 + (lane & 15);
    float f = W[k * 128 + c];
    uint hi = bf16rne(f);
    float hif = __uint_as_float(hi << 16);
    uint lo = __float_as_uint(f - hif) >> 16;  // truncate; residual of residual
    hb[i] = (ushort)hi;
    lb[i] = (ushort)lo;
  }
  *reinterpret_cast<uint4*>(Whi + (size_t)slot * 8) = *reinterpret_cast<uint4*>(hb);
  *reinterpret_cast<uint4*>(Wlo + (size_t)slot * 8) = *reinterpret_cast<uint4*>(lb);
}

// ---------------- GEMM via bf16x3 split MFMA ----------------
// Cb[r][:] = packed bf16( (A[r,:] @ W) * scale[r] ), computed as
// D^T = Wfrag^T @ Afrag^T so each lane owns 1 row x 4 consecutive cols per tile.
// Wave = 16 rows, block = 4 waves = 64 rows. No LDS, no barriers.

__global__ __launch_bounds__(256) void gemm_mfma(const float* __restrict__ A,
                                                 const ushort* __restrict__ Whi,
                                                 const ushort* __restrict__ Wlo,
                                                 const float* __restrict__ scale,
                                                 uint* __restrict__ Cb, int n) {
  const int tid = threadIdx.x;
  const int wave = tid >> 6, lane = tid & 63;
  const int row = blockIdx.x * 64 + wave * 16 + (lane & 15);
  const int kgrp = lane >> 4;  // 0..3
  const bool rowok = row < n;

  f32x4 acc[8];
#pragma unroll
  for (int j = 0; j < 8; ++j) acc[j] = (f32x4){0.f, 0.f, 0.f, 0.f};

#pragma unroll
  for (int kc = 0; kc < 4; ++kc) {
    const float* ap = A + (size_t)row * 128 + kc * 32 + kgrp * 8;
    float4 a0 = make_float4(0.f, 0.f, 0.f, 0.f), a1 = a0;
    if (rowok) {
      a0 = *reinterpret_cast<const float4*>(ap);
      a1 = *reinterpret_cast<const float4*>(ap + 4);
    }
    short8v ahi, alo;
#pragma unroll
    for (int i = 0; i < 8; ++i) {
      float f = (i < 4) ? (&a0.x)[i] : (&a1.x)[i - 4];
      uint hi = bf16rne(f);
      float hif = __uint_as_float(hi << 16);
      uint lo = __float_as_uint(f - hif) >> 16;
      ahi[i] = (short)hi;
      alo[i] = (short)lo;
    }
#pragma unroll
    for (int j = 0; j < 8; ++j) {
      const size_t base = ((size_t)(kc * 8 + j) * 64 + lane) * 8;
      short8v whi = *reinterpret_cast<const short8v*>(Whi + base);
      short8v wlo = *reinterpret_cast<const short8v*>(Wlo + base);
      acc[j] = __builtin_amdgcn_mfma_f32_16x16x32_bf16(whi, ahi, acc[j], 0, 0, 0);
      acc[j] = __builtin_amdgcn_mfma_f32_16x16x32_bf16(whi, alo, acc[j], 0, 0, 0);
      acc[j] = __builtin_amdgcn_mfma_f32_16x16x32_bf16(wlo, ahi, acc[j], 0, 0, 0);
    }
  }

  if (rowok) {
    const float s = scale[row];
#pragma unroll
    for (int j = 0; j < 8; ++j) {
      // lane holds output cols j*16 + kgrp*4 + (0..3) of `row`
      uint u0 = bf16rne(acc[j][0] * s) | (bf16rne(acc[j][1] * s) << 16);
      uint u1 = bf16rne(acc[j][2] * s) | (bf16rne(acc[j][3] * s) << 16);
      *reinterpret_cast<uint2*>(Cb + (size_t)row * 64 + j * 8 + kgrp * 2) =
          make_uint2(u0, u1);
    }
  }
}

// ---------------- aggregation ----------------
// O[i] = relu( dis[i]*( sum_{e:col=i} T'[src] + T'[i] ) + b ),  T' bf16-packed

__global__ __launch_bounds__(256) void agg_kernel(const uint* __restrict__ T,
                                                  const int* __restrict__ indptr,
                                                  const int* __restrict__ csr,
                                                  const float* __restrict__ dis,
                                                  const float* __restrict__ bias,
                                                  float* __restrict__ O, int n) {
  int wid = (blockIdx.x << 2) + (threadIdx.x >> 6);  // one wave per node
  if (wid >= n) return;
  wid = __builtin_amdgcn_readfirstlane(wid);
  const int lane = threadIdx.x & 63;
  const int e0 = indptr[wid], e1 = indptr[wid + 1];
  float ax = 0.f, ay = 0.f;
#define TLOAD(s) T[(size_t)(s) * 64 + lane]
#define BLO(u) __uint_as_float((u) << 16)
#define BHI(u) __uint_as_float((u) & 0xffff0000u)
  int e = e0;
  for (; e + 4 <= e1; e += 4) {
    int s0 = csr[e], s1 = csr[e + 1], s2 = csr[e + 2], s3 = csr[e + 3];
    uint u0 = TLOAD(s0);
    uint u1 = TLOAD(s1);
    uint u2 = TLOAD(s2);
    uint u3 = TLOAD(s3);
    ax += (BLO(u0) + BLO(u1)) + (BLO(u2) + BLO(u3));
    ay += (BHI(u0) + BHI(u1)) + (BHI(u2) + BHI(u3));
  }
  for (; e < e1; ++e) {
    uint u = TLOAD(csr[e]);
    ax += BLO(u);
    ay += BHI(u);
  }
  uint us = TLOAD(wid);  // self loop
  ax += BLO(us);
  ay += BHI(us);
  const float di = dis[wid];
  const float2 b = *reinterpret_cast<const float2*>(bias + lane * 2);
  float ox = fmaxf(fmaf(di, ax, b.x), 0.f);
  float oy = fmaxf(fmaf(di, ay, b.y), 0.f);
  *reinterpret_cast<float2*>(O + (size_t)wid * 128 + lane * 2) = make_float2(ox, oy);
}

// ---------------- pooling over sorted batch ids ----------------

__global__ __launch_bounds__(256) void pool_kernel(const float* __restrict__ H,
                                                   const int* __restrict__ batch,
                                                   float* __restrict__ pooled,
                                                   float* __restrict__ cntg, int n) {
  const int tid = threadIdx.x;
  const int c = tid & 127;
  const int half = tid >> 7;
  const int base = blockIdx.x * 256;
  float acc = 0.f;
  int cnt = 0;
  int curg = -1;
  for (int rr = half; rr < 256; rr += 2) {
    int rowi = base + rr;
    if (rowi >= n) break;
    int g = batch[rowi];
    if (g != curg) {
      if (curg >= 0) {
        atomicAdd(&pooled[curg * 128 + c], acc);
        if (c == 0) atomicAdd(&cntg[curg], (float)cnt);
      }
      curg = g;
      acc = 0.f;
      cnt = 0;
    }
    acc += H[(size_t)rowi * 128 + c];
    cnt++;
  }
  if (curg >= 0) {
    atomicAdd(&pooled[curg * 128 + c], acc);
    if (c == 0) atomicAdd(&cntg[curg], (float)cnt);
  }
}

__global__ __launch_bounds__(128) void final_kernel(const float* __restrict__ pooled,
                                                    const float* __restrict__ cntg,
                                                    const float* __restrict__ Wp,
                                                    const float* __restrict__ bp,
                                                    float* __restrict__ out) {
  const int g = blockIdx.x;
  const int e = threadIdx.x;
  float inv = 1.0f / fmaxf(cntg[g], 1.0f);
  float acc = 0.f;
  for (int c = 0; c < 128; ++c)
    acc = fmaf(pooled[g * 128 + c], Wp[c * 128 + e], acc);
  out[g * 128 + e] = acc * inv + bp[e];
}

// ---------------- launch ----------------

extern "C" void kernel_launch(void* const* d_in, const int* in_sizes, int n_in,
                              void* d_out, int out_size, void* d_ws, size_t ws_size,
                              hipStream_t stream) {
  const float* x = (const float*)d_in[0];
  const int* eidx = (const int*)d_in[1];
  const int* batch = (const int*)d_in[2];
  const float* W1 = (const float*)d_in[3];
  const float* b1 = (const float*)d_in[4];
  const float* W2 = (const float*)d_in[5];
  const float* b2 = (const float*)d_in[6];
  const float* Wp = (const float*)d_in[7];
  const float* bp = (const float*)d_in[8];

  const int n = in_sizes[0] / 128;
  const int E = in_sizes[1] / 2;
  const int* row = eidx;      // edge_index[0] = sources
  const int* col = eidx + E;  // edge_index[1] = targets

  char* ws = (char*)d_ws;
  size_t off = 0;
  auto alloc = [&](size_t bytes) {
    void* p = ws + off;
    off = (off + bytes + 255) & ~(size_t)255;
    return p;
  };
  uint* Tb = (uint*)alloc((size_t)n * 64 * 4);    // bf16-packed messages
  float* B = (float*)alloc((size_t)n * 128 * 4);  // agg output
  float* dis = (float*)alloc((size_t)n * 4);
  int* indptr = (int*)alloc((size_t)(n + 1) * 4);
  int* cnt_i = (int*)alloc((size_t)n * 4);
  int* cursor = (int*)alloc((size_t)n * 4);
  int* csr = (int*)alloc((size_t)E * 4);
  float* pooled = (float*)alloc((size_t)GG * 128 * 4);
  float* cntg = (float*)alloc((size_t)GG * 4);
  int* bsums = (int*)alloc(256 * 4);
  ushort* Whi1 = (ushort*)alloc(2048 * 8 * 2);
  ushort* Wlo1 = (ushort*)alloc(2048 * 8 * 2);
  ushort* Whi2 = (ushort*)alloc(2048 * 8 * 2);
  ushort* Wlo2 = (ushort*)alloc(2048 * 8 * 2);
  (void)off;

  hipMemsetAsync(cnt_i, 0, (size_t)n * 4, stream);
  hipMemsetAsync(pooled, 0, (size_t)GG * 128 * 4, stream);
  hipMemsetAsync(cntg, 0, (size_t)GG * 4, stream);

  count_kernel<<<(E + 255) / 256, 256, 0, stream>>>(col, cnt_i, E);
  const int cpt = (n + 65535) / 65536;
  scan_block_sums<<<256, 256, 0, stream>>>(cnt_i, bsums, n, cpt);
  scan_offsets<<<1, 64, 0, stream>>>(bsums);
  scan_write<<<256, 256, 0, stream>>>(cnt_i, bsums, indptr, cursor, dis, n, cpt, E);
  fill_kernel<<<(E + 255) / 256, 256, 0, stream>>>(row, col, cursor, csr, E);
  wconv_kernel<<<8, 256, 0, stream>>>(W1, Whi1, Wlo1);
  wconv_kernel<<<8, 256, 0, stream>>>(W2, Whi2, Wlo2);

  const int gblocks = (n + 63) / 64;
  gemm_mfma<<<gblocks, 256, 0, stream>>>(x, Whi1, Wlo1, dis, Tb, n);
  agg_kernel<<<(n + 3) / 4, 256, 0, stream>>>(Tb, indptr, csr, dis, b1, B, n);
  gemm_mfma<<<gblocks, 256, 0, stream>>>(B, Whi2, Wlo2, dis, Tb, n);
  agg_kernel<<<(n + 3) / 4, 256, 0, stream>>>(Tb, indptr, csr, dis, b2, B, n);

  pool_kernel<<<(n + 255) / 256, 256, 0, stream>>>(B, batch, pooled, cntg, n);
  final_kernel<<<GG, 128, 0, stream>>>(pooled, cntg, Wp, bp, (float*)d_out);
}

// Round 4
// 336.130 us; speedup vs baseline: 17.1867x; 1.4464x over previous
//
#include <hip/hip_runtime.h>
#include <cstdint>
#include <cstddef>

#define GG 64
#define EPB 4096        // edges per block in hist/bin
#define BUK_SHIFT 9
#define BUK_NODES 512   // nodes per bucket

typedef unsigned int uint;
typedef unsigned short ushort;
typedef __attribute__((ext_vector_type(8))) short short8v;  // 8 bf16 (4 VGPRs)
typedef __attribute__((ext_vector_type(4))) float f32x4;

// ---------------- CSR build: two-level counting sort ----------------

// Pass A: global bucket histogram with block-local LDS pre-aggregation.
__global__ __launch_bounds__(256) void hist_kernel(const int* __restrict__ col,
                                                   int* __restrict__ ghist,
                                                   int E, int nbuk) {
  __shared__ int h[256];
  const int tid = threadIdx.x;
  h[tid] = 0;
  __syncthreads();
  const int base = blockIdx.x * EPB;
#pragma unroll
  for (int j = 0; j < EPB / 256; ++j) {
    int e = base + j * 256 + tid;
    if (e < E) atomicAdd(&h[col[e] >> BUK_SHIFT], 1);
  }
  __syncthreads();
  if (tid < nbuk && h[tid]) atomicAdd(&ghist[tid], h[tid]);
}

// Pass B: exclusive scan of bucket histogram (nbuk <= 256).
__global__ __launch_bounds__(256) void scan_kernel(const int* __restrict__ ghist,
                                                   int* __restrict__ bucketBase,
                                                   int* __restrict__ gcur,
                                                   int nbuk, int E) {
  __shared__ int s[256];
  const int tid = threadIdx.x;
  int v = (tid < nbuk) ? ghist[tid] : 0;
  s[tid] = v;
  __syncthreads();
  for (int off = 1; off < 256; off <<= 1) {
    int t = 0;
    if (tid >= off) t = s[tid - off];
    __syncthreads();
    s[tid] += t;
    __syncthreads();
  }
  int excl = s[tid] - v;
  if (tid < nbuk) {
    bucketBase[tid] = excl;
    gcur[tid] = excl;
  }
  if (tid == 0) bucketBase[nbuk] = E;
}

// Pass C: bin edges by bucket. Packed entry: src | (dst&511)<<17 (needs n < 2^17).
__global__ __launch_bounds__(256) void bin_kernel(const int* __restrict__ row,
                                                  const int* __restrict__ col,
                                                  int* __restrict__ gcur,
                                                  uint* __restrict__ binned, int E) {
  __shared__ int h[256];
  __shared__ int bbase[256];
  __shared__ int lcur[256];
  const int tid = threadIdx.x;
  const int base = blockIdx.x * EPB;
  int src[EPB / 256];
  int dst[EPB / 256];
#pragma unroll
  for (int j = 0; j < EPB / 256; ++j) {
    int e = base + j * 256 + tid;
    if (e < E) {
      src[j] = row[e];
      dst[j] = col[e];
    } else {
      dst[j] = -1;
    }
  }
  h[tid] = 0;
  lcur[tid] = 0;
  __syncthreads();
#pragma unroll
  for (int j = 0; j < EPB / 256; ++j)
    if (dst[j] >= 0) atomicAdd(&h[dst[j] >> BUK_SHIFT], 1);
  __syncthreads();
  if (h[tid] > 0) bbase[tid] = atomicAdd(&gcur[tid], h[tid]);
  __syncthreads();
#pragma unroll
  for (int j = 0; j < EPB / 256; ++j) {
    if (dst[j] >= 0) {
      int b = dst[j] >> BUK_SHIFT;
      int r = atomicAdd(&lcur[b], 1);
      binned[bbase[b] + r] = (uint)src[j] | ((uint)(dst[j] & (BUK_NODES - 1)) << 17);
    }
  }
}

// Pass D: per-bucket node histogram -> indptr/dis, then local scatter into csr.
__global__ __launch_bounds__(256) void build_kernel(const uint* __restrict__ binned,
                                                    const int* __restrict__ bucketBase,
                                                    int* __restrict__ indptr,
                                                    float* __restrict__ dis,
                                                    int* __restrict__ csr,
                                                    int n, int E, int nbuk) {
  __shared__ int h[BUK_NODES];
  __shared__ int off[BUK_NODES];
  __shared__ int ps[256];
  const int tid = threadIdx.x;
  const int b = blockIdx.x;
  const int lo = bucketBase[b], hi = bucketBase[b + 1];
  h[tid] = 0;
  h[tid + 256] = 0;
  __syncthreads();
  for (int i = lo + tid; i < hi; i += 256) atomicAdd(&h[binned[i] >> 17], 1);
  __syncthreads();
  // exclusive scan over 512 entries (2 per thread)
  int a0 = h[2 * tid], a1 = h[2 * tid + 1];
  ps[tid] = a0 + a1;
  __syncthreads();
  for (int o = 1; o < 256; o <<= 1) {
    int t = 0;
    if (tid >= o) t = ps[tid - o];
    __syncthreads();
    ps[tid] += t;
    __syncthreads();
  }
  int pexcl = ps[tid] - (a0 + a1);
  off[2 * tid] = pexcl;
  off[2 * tid + 1] = pexcl + a0;
  __syncthreads();
  const int node0 = b << BUK_SHIFT;
#pragma unroll
  for (int k = tid; k < BUK_NODES; k += 256) {
    int node = node0 + k;
    if (node < n) {
      indptr[node] = lo + off[k];
      dis[node] = rsqrtf((float)(h[k] + 1));
    }
  }
  __syncthreads();
  for (int i = lo + tid; i < hi; i += 256) {
    uint u = binned[i];
    int dlow = u >> 17;
    int s = (int)(u & 0x1FFFFu);
    int r = atomicAdd(&off[dlow], 1);
    csr[lo + r] = s;
  }
  if (b == nbuk - 1 && tid == 0) indptr[n] = E;
}

// ---------------- bf16 split helpers ----------------

__device__ __forceinline__ uint bf16rne(float f) {
  uint u = __float_as_uint(f);
  return (u + 0x7fffu + ((u >> 16) & 1u)) >> 16;
}

// Preconvert W [128][128] f32 into fragment-ready hi/lo bf16 buffers.
__global__ __launch_bounds__(256) void wconv_kernel(const float* __restrict__ W,
                                                    ushort* __restrict__ Whi,
                                                    ushort* __restrict__ Wlo) {
  int slot = blockIdx.x * 256 + threadIdx.x;
  if (slot >= 2048) return;
  int lane = slot & 63;
  int j = (slot >> 6) & 7;
  int kc = slot >> 9;
  ushort hb[8], lb[8];
#pragma unroll
  for (int i = 0; i < 8; ++i) {
    int k = kc * 32 + ((lane >> 4) << 3) + i;
    int c = j * 16 + (lane & 15);
    float f = W[k * 128 + c];
    uint hi = bf16rne(f);
    float hif = __uint_as_float(hi << 16);
    uint lo = __float_as_uint(f - hif) >> 16;
    hb[i] = (ushort)hi;
    lb[i] = (ushort)lo;
  }
  *reinterpret_cast<uint4*>(Whi + (size_t)slot * 8) = *reinterpret_cast<uint4*>(hb);
  *reinterpret_cast<uint4*>(Wlo + (size_t)slot * 8) = *reinterpret_cast<uint4*>(lb);
}

// ---------------- GEMM via bf16x3 split MFMA ----------------

__global__ __launch_bounds__(256) void gemm_mfma(const float* __restrict__ A,
                                                 const ushort* __restrict__ Whi,
                                                 const ushort* __restrict__ Wlo,
                                                 const float* __restrict__ scale,
                                                 uint* __restrict__ Cb, int n) {
  const int tid = threadIdx.x;
  const int wave = tid >> 6, lane = tid & 63;
  const int row = blockIdx.x * 64 + wave * 16 + (lane & 15);
  const int kgrp = lane >> 4;  // 0..3
  const bool rowok = row < n;

  f32x4 acc[8];
#pragma unroll
  for (int j = 0; j < 8; ++j) acc[j] = (f32x4){0.f, 0.f, 0.f, 0.f};

#pragma unroll
  for (int kc = 0; kc < 4; ++kc) {
    const float* ap = A + (size_t)row * 128 + kc * 32 + kgrp * 8;
    float4 a0 = make_float4(0.f, 0.f, 0.f, 0.f), a1 = a0;
    if (rowok) {
      a0 = *reinterpret_cast<const float4*>(ap);
      a1 = *reinterpret_cast<const float4*>(ap + 4);
    }
    short8v ahi, alo;
#pragma unroll
    for (int i = 0; i < 8; ++i) {
      float f = (i < 4) ? (&a0.x)[i] : (&a1.x)[i - 4];
      uint hi = bf16rne(f);
      float hif = __uint_as_float(hi << 16);
      uint lo = __float_as_uint(f - hif) >> 16;
      ahi[i] = (short)hi;
      alo[i] = (short)lo;
    }
#pragma unroll
    for (int j = 0; j < 8; ++j) {
      const size_t base = ((size_t)(kc * 8 + j) * 64 + lane) * 8;
      short8v whi = *reinterpret_cast<const short8v*>(Whi + base);
      short8v wlo = *reinterpret_cast<const short8v*>(Wlo + base);
      acc[j] = __builtin_amdgcn_mfma_f32_16x16x32_bf16(whi, ahi, acc[j], 0, 0, 0);
      acc[j] = __builtin_amdgcn_mfma_f32_16x16x32_bf16(whi, alo, acc[j], 0, 0, 0);
      acc[j] = __builtin_amdgcn_mfma_f32_16x16x32_bf16(wlo, ahi, acc[j], 0, 0, 0);
    }
  }

  if (rowok) {
    const float s = scale[row];
#pragma unroll
    for (int j = 0; j < 8; ++j) {
      uint u0 = bf16rne(acc[j][0] * s) | (bf16rne(acc[j][1] * s) << 16);
      uint u1 = bf16rne(acc[j][2] * s) | (bf16rne(acc[j][3] * s) << 16);
      *reinterpret_cast<uint2*>(Cb + (size_t)row * 64 + j * 8 + kgrp * 2) =
          make_uint2(u0, u1);
    }
  }
}

// ---------------- aggregation ----------------

__global__ __launch_bounds__(256) void agg_kernel(const uint* __restrict__ T,
                                                  const int* __restrict__ indptr,
                                                  const int* __restrict__ csr,
                                                  const float* __restrict__ dis,
                                                  const float* __restrict__ bias,
                                                  float* __restrict__ O, int n) {
  int wid = (blockIdx.x << 2) + (threadIdx.x >> 6);  // one wave per node
  if (wid >= n) return;
  wid = __builtin_amdgcn_readfirstlane(wid);
  const int lane = threadIdx.x & 63;
  const int e0 = indptr[wid], e1 = indptr[wid + 1];
  float ax = 0.f, ay = 0.f;
#define TLOAD(s) T[(size_t)(s) * 64 + lane]
#define BLO(u) __uint_as_float((u) << 16)
#define BHI(u) __uint_as_float((u) & 0xffff0000u)
  int e = e0;
  for (; e + 8 <= e1; e += 8) {
    int s0 = csr[e], s1 = csr[e + 1], s2 = csr[e + 2], s3 = csr[e + 3];
    int s4 = csr[e + 4], s5 = csr[e + 5], s6 = csr[e + 6], s7 = csr[e + 7];
    uint u0 = TLOAD(s0), u1 = TLOAD(s1), u2 = TLOAD(s2), u3 = TLOAD(s3);
    uint u4 = TLOAD(s4), u5 = TLOAD(s5), u6 = TLOAD(s6), u7 = TLOAD(s7);
    ax += ((BLO(u0) + BLO(u1)) + (BLO(u2) + BLO(u3))) +
          ((BLO(u4) + BLO(u5)) + (BLO(u6) + BLO(u7)));
    ay += ((BHI(u0) + BHI(u1)) + (BHI(u2) + BHI(u3))) +
          ((BHI(u4) + BHI(u5)) + (BHI(u6) + BHI(u7)));
  }
  for (; e + 4 <= e1; e += 4) {
    int s0 = csr[e], s1 = csr[e + 1], s2 = csr[e + 2], s3 = csr[e + 3];
    uint u0 = TLOAD(s0), u1 = TLOAD(s1), u2 = TLOAD(s2), u3 = TLOAD(s3);
    ax += (BLO(u0) + BLO(u1)) + (BLO(u2) + BLO(u3));
    ay += (BHI(u0) + BHI(u1)) + (BHI(u2) + BHI(u3));
  }
  for (; e < e1; ++e) {
    uint u = TLOAD(csr[e]);
    ax += BLO(u);
    ay += BHI(u);
  }
  uint us = TLOAD(wid);  // self loop
  ax += BLO(us);
  ay += BHI(us);
  const float di = dis[wid];
  const float2 b = *reinterpret_cast<const float2*>(bias + lane * 2);
  float ox = fmaxf(fmaf(di, ax, b.x), 0.f);
  float oy = fmaxf(fmaf(di, ay, b.y), 0.f);
  *reinterpret_cast<float2*>(O + (size_t)wid * 128 + lane * 2) = make_float2(ox, oy);
}

// ---------------- pooling over sorted batch ids ----------------

__global__ __launch_bounds__(256) void pool_kernel(const float* __restrict__ H,
                                                   const int* __restrict__ batch,
                                                   float* __restrict__ pooled,
                                                   float* __restrict__ cntg, int n) {
  const int tid = threadIdx.x;
  const int c = tid & 127;
  const int half = tid >> 7;
  const int base = blockIdx.x * 256;
  float acc = 0.f;
  int cnt = 0;
  int curg = -1;
  for (int rr = half; rr < 256; rr += 2) {
    int rowi = base + rr;
    if (rowi >= n) break;
    int g = batch[rowi];
    if (g != curg) {
      if (curg >= 0) {
        atomicAdd(&pooled[curg * 128 + c], acc);
        if (c == 0) atomicAdd(&cntg[curg], (float)cnt);
      }
      curg = g;
      acc = 0.f;
      cnt = 0;
    }
    acc += H[(size_t)rowi * 128 + c];
    cnt++;
  }
  if (curg >= 0) {
    atomicAdd(&pooled[curg * 128 + c], acc);
    if (c == 0) atomicAdd(&cntg[curg], (float)cnt);
  }
}

__global__ __launch_bounds__(128) void final_kernel(const float* __restrict__ pooled,
                                                    const float* __restrict__ cntg,
                                                    const float* __restrict__ Wp,
                                                    const float* __restrict__ bp,
                                                    float* __restrict__ out) {
  const int g = blockIdx.x;
  const int e = threadIdx.x;
  float inv = 1.0f / fmaxf(cntg[g], 1.0f);
  float acc = 0.f;
  for (int c = 0; c < 128; ++c)
    acc = fmaf(pooled[g * 128 + c], Wp[c * 128 + e], acc);
  out[g * 128 + e] = acc * inv + bp[e];
}

// ---------------- launch ----------------

extern "C" void kernel_launch(void* const* d_in, const int* in_sizes, int n_in,
                              void* d_out, int out_size, void* d_ws, size_t ws_size,
                              hipStream_t stream) {
  const float* x = (const float*)d_in[0];
  const int* eidx = (const int*)d_in[1];
  const int* batch = (const int*)d_in[2];
  const float* W1 = (const float*)d_in[3];
  const float* b1 = (const float*)d_in[4];
  const float* W2 = (const float*)d_in[5];
  const float* b2 = (const float*)d_in[6];
  const float* Wp = (const float*)d_in[7];
  const float* bp = (const float*)d_in[8];

  const int n = in_sizes[0] / 128;
  const int E = in_sizes[1] / 2;
  const int* row = eidx;      // edge_index[0] = sources
  const int* col = eidx + E;  // edge_index[1] = targets
  const int nbuk = (n + BUK_NODES - 1) >> BUK_SHIFT;

  char* ws = (char*)d_ws;
  size_t off = 0;
  auto alloc = [&](size_t bytes) {
    void* p = ws + off;
    off = (off + bytes + 255) & ~(size_t)255;
    return p;
  };
  uint* Tb = (uint*)alloc((size_t)n * 64 * 4);    // bf16-packed messages
  float* B = (float*)alloc((size_t)n * 128 * 4);  // agg output
  float* dis = (float*)alloc((size_t)n * 4);
  int* indptr = (int*)alloc((size_t)(n + 1) * 4);
  int* csr = (int*)alloc((size_t)E * 4);
  uint* binned = (uint*)alloc((size_t)E * 4);
  int* ghist = (int*)alloc(256 * 4);
  int* bucketBase = (int*)alloc(257 * 4);
  int* gcur = (int*)alloc(256 * 4);
  float* pooled = (float*)alloc((size_t)GG * 128 * 4);
  float* cntg = (float*)alloc((size_t)GG * 4);
  ushort* Whi1 = (ushort*)alloc(2048 * 8 * 2);
  ushort* Wlo1 = (ushort*)alloc(2048 * 8 * 2);
  ushort* Whi2 = (ushort*)alloc(2048 * 8 * 2);
  ushort* Wlo2 = (ushort*)alloc(2048 * 8 * 2);
  (void)off;

  hipMemsetAsync(ghist, 0, 256 * 4, stream);
  hipMemsetAsync(pooled, 0, (size_t)GG * 128 * 4, stream);
  hipMemsetAsync(cntg, 0, (size_t)GG * 4, stream);

  const int eblocks = (E + EPB - 1) / EPB;
  hist_kernel<<<eblocks, 256, 0, stream>>>(col, ghist, E, nbuk);
  scan_kernel<<<1, 256, 0, stream>>>(ghist, bucketBase, gcur, nbuk, E);
  bin_kernel<<<eblocks, 256, 0, stream>>>(row, col, gcur, binned, E);
  build_kernel<<<nbuk, 256, 0, stream>>>(binned, bucketBase, indptr, dis, csr, n, E, nbuk);
  wconv_kernel<<<8, 256, 0, stream>>>(W1, Whi1, Wlo1);
  wconv_kernel<<<8, 256, 0, stream>>>(W2, Whi2, Wlo2);

  const int gblocks = (n + 63) / 64;
  gemm_mfma<<<gblocks, 256, 0, stream>>>(x, Whi1, Wlo1, dis, Tb, n);
  agg_kernel<<<(n + 3) / 4, 256, 0, stream>>>(Tb, indptr, csr, dis, b1, B, n);
  gemm_mfma<<<gblocks, 256, 0, stream>>>(B, Whi2, Wlo2, dis, Tb, n);
  agg_kernel<<<(n + 3) / 4, 256, 0, stream>>>(Tb, indptr, csr, dis, b2, B, n);

  pool_kernel<<<(n + 255) / 256, 256, 0, stream>>>(B, batch, pooled, cntg, n);
  final_kernel<<<GG, 128, 0, stream>>>(pooled, cntg, Wp, bp, (float*)d_out);
}

// Round 5
// 287.537 us; speedup vs baseline: 20.0912x; 1.1690x over previous
//
#include <hip/hip_runtime.h>
#include <cstdint>
#include <cstddef>

#define GG 64
#define EPB 4096        // edges per block in hist/bin
#define BUK_SHIFT 9
#define BUK_NODES 512   // nodes per bucket
#define PCHUNK 64       // rows per pool block

typedef unsigned int uint;
typedef unsigned short ushort;
typedef __attribute__((ext_vector_type(8))) short short8v;  // 8 bf16 (4 VGPRs)
typedef __attribute__((ext_vector_type(4))) float f32x4;

// ---------------- CSR build: two-level counting sort ----------------

// Pass A: global bucket histogram with block-local LDS pre-aggregation.
__global__ __launch_bounds__(256) void hist_kernel(const int* __restrict__ col,
                                                   int* __restrict__ ghist,
                                                   int E, int nbuk) {
  __shared__ int h[256];
  const int tid = threadIdx.x;
  h[tid] = 0;
  __syncthreads();
  const int base = blockIdx.x * EPB;
#pragma unroll
  for (int j = 0; j < EPB / 256; ++j) {
    int e = base + j * 256 + tid;
    if (e < E) atomicAdd(&h[col[e] >> BUK_SHIFT], 1);
  }
  __syncthreads();
  if (tid < nbuk && h[tid]) atomicAdd(&ghist[tid], h[tid]);
}

// Pass B: exclusive scan of bucket histogram (nbuk <= 256).
__global__ __launch_bounds__(256) void scan_kernel(const int* __restrict__ ghist,
                                                   int* __restrict__ bucketBase,
                                                   int* __restrict__ gcur,
                                                   int nbuk, int E) {
  __shared__ int s[256];
  const int tid = threadIdx.x;
  int v = (tid < nbuk) ? ghist[tid] : 0;
  s[tid] = v;
  __syncthreads();
  for (int off = 1; off < 256; off <<= 1) {
    int t = 0;
    if (tid >= off) t = s[tid - off];
    __syncthreads();
    s[tid] += t;
    __syncthreads();
  }
  int excl = s[tid] - v;
  if (tid < nbuk) {
    bucketBase[tid] = excl;
    gcur[tid] = excl;
  }
  if (tid == 0) bucketBase[nbuk] = E;
}

// Pass C: bin edges by bucket. Packed entry: src | (dst&511)<<17 (needs n < 2^17).
__global__ __launch_bounds__(256) void bin_kernel(const int* __restrict__ row,
                                                  const int* __restrict__ col,
                                                  int* __restrict__ gcur,
                                                  uint* __restrict__ binned, int E) {
  __shared__ int h[256];
  __shared__ int bbase[256];
  __shared__ int lcur[256];
  const int tid = threadIdx.x;
  const int base = blockIdx.x * EPB;
  int src[EPB / 256];
  int dst[EPB / 256];
#pragma unroll
  for (int j = 0; j < EPB / 256; ++j) {
    int e = base + j * 256 + tid;
    if (e < E) {
      src[j] = row[e];
      dst[j] = col[e];
    } else {
      dst[j] = -1;
    }
  }
  h[tid] = 0;
  lcur[tid] = 0;
  __syncthreads();
#pragma unroll
  for (int j = 0; j < EPB / 256; ++j)
    if (dst[j] >= 0) atomicAdd(&h[dst[j] >> BUK_SHIFT], 1);
  __syncthreads();
  if (h[tid] > 0) bbase[tid] = atomicAdd(&gcur[tid], h[tid]);
  __syncthreads();
#pragma unroll
  for (int j = 0; j < EPB / 256; ++j) {
    if (dst[j] >= 0) {
      int b = dst[j] >> BUK_SHIFT;
      int r = atomicAdd(&lcur[b], 1);
      binned[bbase[b] + r] = (uint)src[j] | ((uint)(dst[j] & (BUK_NODES - 1)) << 17);
    }
  }
}

// Pass D: per-bucket node histogram -> indptr/dis, then local scatter into csr.
__global__ __launch_bounds__(256) void build_kernel(const uint* __restrict__ binned,
                                                    const int* __restrict__ bucketBase,
                                                    int* __restrict__ indptr,
                                                    float* __restrict__ dis,
                                                    int* __restrict__ csr,
                                                    int n, int E, int nbuk) {
  __shared__ int h[BUK_NODES];
  __shared__ int off[BUK_NODES];
  __shared__ int ps[256];
  const int tid = threadIdx.x;
  const int b = blockIdx.x;
  const int lo = bucketBase[b], hi = bucketBase[b + 1];
  h[tid] = 0;
  h[tid + 256] = 0;
  __syncthreads();
  for (int i = lo + tid; i < hi; i += 256) atomicAdd(&h[binned[i] >> 17], 1);
  __syncthreads();
  // exclusive scan over 512 entries (2 per thread)
  int a0 = h[2 * tid], a1 = h[2 * tid + 1];
  ps[tid] = a0 + a1;
  __syncthreads();
  for (int o = 1; o < 256; o <<= 1) {
    int t = 0;
    if (tid >= o) t = ps[tid - o];
    __syncthreads();
    ps[tid] += t;
    __syncthreads();
  }
  int pexcl = ps[tid] - (a0 + a1);
  off[2 * tid] = pexcl;
  off[2 * tid + 1] = pexcl + a0;
  __syncthreads();
  const int node0 = b << BUK_SHIFT;
#pragma unroll
  for (int k = tid; k < BUK_NODES; k += 256) {
    int node = node0 + k;
    if (node < n) {
      indptr[node] = lo + off[k];
      dis[node] = rsqrtf((float)(h[k] + 1));
    }
  }
  __syncthreads();
  for (int i = lo + tid; i < hi; i += 256) {
    uint u = binned[i];
    int dlow = u >> 17;
    int s = (int)(u & 0x1FFFFu);
    int r = atomicAdd(&off[dlow], 1);
    csr[lo + r] = s;
  }
  if (b == nbuk - 1 && tid == 0) indptr[n] = E;
}

// ---------------- bf16 split helpers ----------------

__device__ __forceinline__ uint bf16rne(float f) {
  uint u = __float_as_uint(f);
  return (u + 0x7fffu + ((u >> 16) & 1u)) >> 16;
}

// Preconvert W [128][128] f32 into fragment-ready hi/lo bf16 buffers.
__global__ __launch_bounds__(256) void wconv_kernel(const float* __restrict__ W,
                                                    ushort* __restrict__ Whi,
                                                    ushort* __restrict__ Wlo) {
  int slot = blockIdx.x * 256 + threadIdx.x;
  if (slot >= 2048) return;
  int lane = slot & 63;
  int j = (slot >> 6) & 7;
  int kc = slot >> 9;
  ushort hb[8], lb[8];
#pragma unroll
  for (int i = 0; i < 8; ++i) {
    int k = kc * 32 + ((lane >> 4) << 3) + i;
    int c = j * 16 + (lane & 15);
    float f = W[k * 128 + c];
    uint hi = bf16rne(f);
    float hif = __uint_as_float(hi << 16);
    uint lo = __float_as_uint(f - hif) >> 16;
    hb[i] = (ushort)hi;
    lb[i] = (ushort)lo;
  }
  *reinterpret_cast<uint4*>(Whi + (size_t)slot * 8) = *reinterpret_cast<uint4*>(hb);
  *reinterpret_cast<uint4*>(Wlo + (size_t)slot * 8) = *reinterpret_cast<uint4*>(lb);
}

// ---------------- GEMM via bf16x3 split MFMA ----------------

__global__ __launch_bounds__(256) void gemm_mfma(const float* __restrict__ A,
                                                 const ushort* __restrict__ Whi,
                                                 const ushort* __restrict__ Wlo,
                                                 const float* __restrict__ scale,
                                                 uint* __restrict__ Cb, int n) {
  const int tid = threadIdx.x;
  const int wave = tid >> 6, lane = tid & 63;
  const int row = blockIdx.x * 64 + wave * 16 + (lane & 15);
  const int kgrp = lane >> 4;  // 0..3
  const bool rowok = row < n;

  f32x4 acc[8];
#pragma unroll
  for (int j = 0; j < 8; ++j) acc[j] = (f32x4){0.f, 0.f, 0.f, 0.f};

#pragma unroll
  for (int kc = 0; kc < 4; ++kc) {
    const float* ap = A + (size_t)row * 128 + kc * 32 + kgrp * 8;
    float4 a0 = make_float4(0.f, 0.f, 0.f, 0.f), a1 = a0;
    if (rowok) {
      a0 = *reinterpret_cast<const float4*>(ap);
      a1 = *reinterpret_cast<const float4*>(ap + 4);
    }
    short8v ahi, alo;
#pragma unroll
    for (int i = 0; i < 8; ++i) {
      float f = (i < 4) ? (&a0.x)[i] : (&a1.x)[i - 4];
      uint hi = bf16rne(f);
      float hif = __uint_as_float(hi << 16);
      uint lo = __float_as_uint(f - hif) >> 16;
      ahi[i] = (short)hi;
      alo[i] = (short)lo;
    }
#pragma unroll
    for (int j = 0; j < 8; ++j) {
      const size_t base = ((size_t)(kc * 8 + j) * 64 + lane) * 8;
      short8v whi = *reinterpret_cast<const short8v*>(Whi + base);
      short8v wlo = *reinterpret_cast<const short8v*>(Wlo + base);
      acc[j] = __builtin_amdgcn_mfma_f32_16x16x32_bf16(whi, ahi, acc[j], 0, 0, 0);
      acc[j] = __builtin_amdgcn_mfma_f32_16x16x32_bf16(whi, alo, acc[j], 0, 0, 0);
      acc[j] = __builtin_amdgcn_mfma_f32_16x16x32_bf16(wlo, ahi, acc[j], 0, 0, 0);
    }
  }

  if (rowok) {
    const float s = scale[row];
#pragma unroll
    for (int j = 0; j < 8; ++j) {
      uint u0 = bf16rne(acc[j][0] * s) | (bf16rne(acc[j][1] * s) << 16);
      uint u1 = bf16rne(acc[j][2] * s) | (bf16rne(acc[j][3] * s) << 16);
      *reinterpret_cast<uint2*>(Cb + (size_t)row * 64 + j * 8 + kgrp * 2) =
          make_uint2(u0, u1);
    }
  }
}

// ---------------- aggregation ----------------

__global__ __launch_bounds__(256) void agg_kernel(const uint* __restrict__ T,
                                                  const int* __restrict__ indptr,
                                                  const int* __restrict__ csr,
                                                  const float* __restrict__ dis,
                                                  const float* __restrict__ bias,
                                                  float* __restrict__ O, int n) {
  int wid = (blockIdx.x << 2) + (threadIdx.x >> 6);  // one wave per node
  if (wid >= n) return;
  wid = __builtin_amdgcn_readfirstlane(wid);
  const int lane = threadIdx.x & 63;
  const int e0 = indptr[wid], e1 = indptr[wid + 1];
  float ax = 0.f, ay = 0.f;
#define TLOAD(s) T[(size_t)(s) * 64 + lane]
#define BLO(u) __uint_as_float((u) << 16)
#define BHI(u) __uint_as_float((u) & 0xffff0000u)
  int e = e0;
  for (; e + 8 <= e1; e += 8) {
    int s0 = csr[e], s1 = csr[e + 1], s2 = csr[e + 2], s3 = csr[e + 3];
    int s4 = csr[e + 4], s5 = csr[e + 5], s6 = csr[e + 6], s7 = csr[e + 7];
    uint u0 = TLOAD(s0), u1 = TLOAD(s1), u2 = TLOAD(s2), u3 = TLOAD(s3);
    uint u4 = TLOAD(s4), u5 = TLOAD(s5), u6 = TLOAD(s6), u7 = TLOAD(s7);
    ax += ((BLO(u0) + BLO(u1)) + (BLO(u2) + BLO(u3))) +
          ((BLO(u4) + BLO(u5)) + (BLO(u6) + BLO(u7)));
    ay += ((BHI(u0) + BHI(u1)) + (BHI(u2) + BHI(u3))) +
          ((BHI(u4) + BHI(u5)) + (BHI(u6) + BHI(u7)));
  }
  for (; e + 4 <= e1; e += 4) {
    int s0 = csr[e], s1 = csr[e + 1], s2 = csr[e + 2], s3 = csr[e + 3];
    uint u0 = TLOAD(s0), u1 = TLOAD(s1), u2 = TLOAD(s2), u3 = TLOAD(s3);
    ax += (BLO(u0) + BLO(u1)) + (BLO(u2) + BLO(u3));
    ay += (BHI(u0) + BHI(u1)) + (BHI(u2) + BHI(u3));
  }
  for (; e < e1; ++e) {
    uint u = TLOAD(csr[e]);
    ax += BLO(u);
    ay += BHI(u);
  }
  uint us = TLOAD(wid);  // self loop
  ax += BLO(us);
  ay += BHI(us);
  const float di = dis[wid];
  const float2 b = *reinterpret_cast<const float2*>(bias + lane * 2);
  float ox = fmaxf(fmaf(di, ax, b.x), 0.f);
  float oy = fmaxf(fmaf(di, ay, b.y), 0.f);
  *reinterpret_cast<float2*>(O + (size_t)wid * 128 + lane * 2) = make_float2(ox, oy);
}

// ---------------- pooling over sorted batch ids ----------------
// CHUNK=64 rows/block, float4/thread, LDS tree reduce on the (common)
// single-segment fast path; per-thread run flushing on boundary blocks.

__global__ __launch_bounds__(256) void pool_kernel(const float* __restrict__ H,
                                                   const int* __restrict__ batch,
                                                   float* __restrict__ pooled,
                                                   float* __restrict__ cntg, int n) {
  __shared__ float sd[256 * 4];
  const int tid = threadIdx.x;
  const int c4 = (tid & 31) << 2;  // column base
  const int rs = tid >> 5;         // 0..7 row subgroup
  const int base = blockIdx.x * PCHUNK;
  const int lim = min(base + PCHUNK, n);
  const int g0 = batch[base];
  const int gN = batch[lim - 1];
  float4 acc = make_float4(0.f, 0.f, 0.f, 0.f);
  if (g0 == gN) {
    for (int r = base + rs; r < lim; r += 8) {
      float4 v = *reinterpret_cast<const float4*>(H + (size_t)r * 128 + c4);
      acc.x += v.x; acc.y += v.y; acc.z += v.z; acc.w += v.w;
    }
    *reinterpret_cast<float4*>(&sd[tid * 4]) = acc;
    __syncthreads();
    if (tid < 128) {
      float4 o = *reinterpret_cast<float4*>(&sd[(tid + 128) * 4]);
      acc.x += o.x; acc.y += o.y; acc.z += o.z; acc.w += o.w;
      *reinterpret_cast<float4*>(&sd[tid * 4]) = acc;
    }
    __syncthreads();
    if (tid < 64) {
      float4 o = *reinterpret_cast<float4*>(&sd[(tid + 64) * 4]);
      acc.x += o.x; acc.y += o.y; acc.z += o.z; acc.w += o.w;
      *reinterpret_cast<float4*>(&sd[tid * 4]) = acc;
    }
    __syncthreads();
    if (tid < 32) {
      float4 o = *reinterpret_cast<float4*>(&sd[(tid + 32) * 4]);
      acc.x += o.x; acc.y += o.y; acc.z += o.z; acc.w += o.w;
      atomicAdd(&pooled[g0 * 128 + c4 + 0], acc.x);
      atomicAdd(&pooled[g0 * 128 + c4 + 1], acc.y);
      atomicAdd(&pooled[g0 * 128 + c4 + 2], acc.z);
      atomicAdd(&pooled[g0 * 128 + c4 + 3], acc.w);
      if (tid == 0) atomicAdd(&cntg[g0], (float)(lim - base));
    }
  } else {
    int curg = -1, cnt = 0;
    for (int r = base + rs; r < lim; r += 8) {
      int g = batch[r];
      if (g != curg) {
        if (curg >= 0) {
          atomicAdd(&pooled[curg * 128 + c4 + 0], acc.x);
          atomicAdd(&pooled[curg * 128 + c4 + 1], acc.y);
          atomicAdd(&pooled[curg * 128 + c4 + 2], acc.z);
          atomicAdd(&pooled[curg * 128 + c4 + 3], acc.w);
          if ((tid & 31) == 0) atomicAdd(&cntg[curg], (float)cnt);
        }
        curg = g;
        acc = make_float4(0.f, 0.f, 0.f, 0.f);
        cnt = 0;
      }
      float4 v = *reinterpret_cast<const float4*>(H + (size_t)r * 128 + c4);
      acc.x += v.x; acc.y += v.y; acc.z += v.z; acc.w += v.w;
      cnt++;
    }
    if (curg >= 0) {
      atomicAdd(&pooled[curg * 128 + c4 + 0], acc.x);
      atomicAdd(&pooled[curg * 128 + c4 + 1], acc.y);
      atomicAdd(&pooled[curg * 128 + c4 + 2], acc.z);
      atomicAdd(&pooled[curg * 128 + c4 + 3], acc.w);
      if ((tid & 31) == 0) atomicAdd(&cntg[curg], (float)cnt);
    }
  }
}

__global__ __launch_bounds__(128) void final_kernel(const float* __restrict__ pooled,
                                                    const float* __restrict__ cntg,
                                                    const float* __restrict__ Wp,
                                                    const float* __restrict__ bp,
                                                    float* __restrict__ out) {
  const int g = blockIdx.x;
  const int e = threadIdx.x;
  float inv = 1.0f / fmaxf(cntg[g], 1.0f);
  float acc = 0.f;
  for (int c = 0; c < 128; ++c)
    acc = fmaf(pooled[g * 128 + c], Wp[c * 128 + e], acc);
  out[g * 128 + e] = acc * inv + bp[e];
}

// ---------------- launch ----------------

extern "C" void kernel_launch(void* const* d_in, const int* in_sizes, int n_in,
                              void* d_out, int out_size, void* d_ws, size_t ws_size,
                              hipStream_t stream) {
  const float* x = (const float*)d_in[0];
  const int* eidx = (const int*)d_in[1];
  const int* batch = (const int*)d_in[2];
  const float* W1 = (const float*)d_in[3];
  const float* b1 = (const float*)d_in[4];
  const float* W2 = (const float*)d_in[5];
  const float* b2 = (const float*)d_in[6];
  const float* Wp = (const float*)d_in[7];
  const float* bp = (const float*)d_in[8];

  const int n = in_sizes[0] / 128;
  const int E = in_sizes[1] / 2;
  const int* row = eidx;      // edge_index[0] = sources
  const int* col = eidx + E;  // edge_index[1] = targets
  const int nbuk = (n + BUK_NODES - 1) >> BUK_SHIFT;

  char* ws = (char*)d_ws;
  size_t off = 0;
  auto alloc = [&](size_t bytes) {
    void* p = ws + off;
    off = (off + bytes + 255) & ~(size_t)255;
    return p;
  };
  uint* Tb = (uint*)alloc((size_t)n * 64 * 4);    // bf16-packed messages
  float* B = (float*)alloc((size_t)n * 128 * 4);  // agg output
  float* dis = (float*)alloc((size_t)n * 4);
  int* indptr = (int*)alloc((size_t)(n + 1) * 4);
  int* csr = (int*)alloc((size_t)E * 4);
  uint* binned = (uint*)alloc((size_t)E * 4);
  int* ghist = (int*)alloc(256 * 4);
  int* bucketBase = (int*)alloc(257 * 4);
  int* gcur = (int*)alloc(256 * 4);
  float* pooled = (float*)alloc((size_t)GG * 128 * 4);
  float* cntg = (float*)alloc((size_t)GG * 4);
  ushort* Whi1 = (ushort*)alloc(2048 * 8 * 2);
  ushort* Wlo1 = (ushort*)alloc(2048 * 8 * 2);
  ushort* Whi2 = (ushort*)alloc(2048 * 8 * 2);
  ushort* Wlo2 = (ushort*)alloc(2048 * 8 * 2);
  (void)off;

  hipMemsetAsync(ghist, 0, 256 * 4, stream);
  hipMemsetAsync(pooled, 0, (size_t)GG * 128 * 4, stream);
  hipMemsetAsync(cntg, 0, (size_t)GG * 4, stream);

  const int eblocks = (E + EPB - 1) / EPB;
  hist_kernel<<<eblocks, 256, 0, stream>>>(col, ghist, E, nbuk);
  scan_kernel<<<1, 256, 0, stream>>>(ghist, bucketBase, gcur, nbuk, E);
  bin_kernel<<<eblocks, 256, 0, stream>>>(row, col, gcur, binned, E);
  build_kernel<<<nbuk, 256, 0, stream>>>(binned, bucketBase, indptr, dis, csr, n, E, nbuk);
  wconv_kernel<<<8, 256, 0, stream>>>(W1, Whi1, Wlo1);
  wconv_kernel<<<8, 256, 0, stream>>>(W2, Whi2, Wlo2);

  const int gblocks = (n + 63) / 64;
  gemm_mfma<<<gblocks, 256, 0, stream>>>(x, Whi1, Wlo1, dis, Tb, n);
  agg_kernel<<<(n + 3) / 4, 256, 0, stream>>>(Tb, indptr, csr, dis, b1, B, n);
  gemm_mfma<<<gblocks, 256, 0, stream>>>(B, Whi2, Wlo2, dis, Tb, n);
  agg_kernel<<<(n + 3) / 4, 256, 0, stream>>>(Tb, indptr, csr, dis, b2, B, n);

  pool_kernel<<<(n + PCHUNK - 1) / PCHUNK, 256, 0, stream>>>(B, batch, pooled, cntg, n);
  final_kernel<<<GG, 128, 0, stream>>>(pooled, cntg, Wp, bp, (float*)d_out);
}

// Round 6
// 270.897 us; speedup vs baseline: 21.3253x; 1.0614x over previous
//
#include <hip/hip_runtime.h>
#include <cstdint>
#include <cstddef>

#define GG 64
#define EPB 4096        // edges per block in hist/bin
#define BUK_SHIFT 9
#define BUK_NODES 512   // nodes per bucket
#define PCHUNK 64       // rows per pool block
#define NCH 8           // source chunks (src>>14), 16384 nodes = 3.2MB of Tb per chunk

typedef unsigned int uint;
typedef unsigned short ushort;
typedef __attribute__((ext_vector_type(8))) short short8v;  // 8 bf16 (4 VGPRs)
typedef __attribute__((ext_vector_type(4))) float f32x4;

__device__ __forceinline__ float blo(uint u) { return __uint_as_float(u << 16); }
__device__ __forceinline__ float bhi(uint u) { return __uint_as_float(u & 0xffff0000u); }

__device__ __forceinline__ uint bf16rne(float f) {
  uint u = __float_as_uint(f);
  return (u + 0x7fffu + ((u >> 16) & 1u)) >> 16;
}

// ---------------- CSR build: two-level counting sort ----------------

// Pass A: global bucket histogram with block-local LDS pre-aggregation.
__global__ __launch_bounds__(256) void hist_kernel(const int* __restrict__ col,
                                                   int* __restrict__ ghist,
                                                   int E, int nbuk) {
  __shared__ int h[256];
  const int tid = threadIdx.x;
  h[tid] = 0;
  __syncthreads();
  const int base = blockIdx.x * EPB;
#pragma unroll
  for (int j = 0; j < EPB / 256; ++j) {
    int e = base + j * 256 + tid;
    if (e < E) atomicAdd(&h[col[e] >> BUK_SHIFT], 1);
  }
  __syncthreads();
  if (tid < nbuk && h[tid]) atomicAdd(&ghist[tid], h[tid]);
}

// Pass B: exclusive scan of bucket histogram (nbuk <= 256).
__global__ __launch_bounds__(256) void scan_kernel(const int* __restrict__ ghist,
                                                   int* __restrict__ bucketBase,
                                                   int* __restrict__ gcur,
                                                   int nbuk, int E) {
  __shared__ int s[256];
  const int tid = threadIdx.x;
  int v = (tid < nbuk) ? ghist[tid] : 0;
  s[tid] = v;
  __syncthreads();
  for (int off = 1; off < 256; off <<= 1) {
    int t = 0;
    if (tid >= off) t = s[tid - off];
    __syncthreads();
    s[tid] += t;
    __syncthreads();
  }
  int excl = s[tid] - v;
  if (tid < nbuk) {
    bucketBase[tid] = excl;
    gcur[tid] = excl;
  }
  if (tid == 0) bucketBase[nbuk] = E;
}

// Pass C: bin edges by bucket. Packed entry: src | (dst&511)<<17 (needs n < 2^17).
__global__ __launch_bounds__(256) void bin_kernel(const int* __restrict__ row,
                                                  const int* __restrict__ col,
                                                  int* __restrict__ gcur,
                                                  uint* __restrict__ binned, int E) {
  __shared__ int h[256];
  __shared__ int bbase[256];
  __shared__ int lcur[256];
  const int tid = threadIdx.x;
  const int base = blockIdx.x * EPB;
  int src[EPB / 256];
  int dst[EPB / 256];
#pragma unroll
  for (int j = 0; j < EPB / 256; ++j) {
    int e = base + j * 256 + tid;
    if (e < E) {
      src[j] = row[e];
      dst[j] = col[e];
    } else {
      dst[j] = -1;
    }
  }
  h[tid] = 0;
  lcur[tid] = 0;
  __syncthreads();
#pragma unroll
  for (int j = 0; j < EPB / 256; ++j)
    if (dst[j] >= 0) atomicAdd(&h[dst[j] >> BUK_SHIFT], 1);
  __syncthreads();
  if (h[tid] > 0) bbase[tid] = atomicAdd(&gcur[tid], h[tid]);
  __syncthreads();
#pragma unroll
  for (int j = 0; j < EPB / 256; ++j) {
    if (dst[j] >= 0) {
      int b = dst[j] >> BUK_SHIFT;
      int r = atomicAdd(&lcur[b], 1);
      binned[bbase[b] + r] = (uint)src[j] | ((uint)(dst[j] & (BUK_NODES - 1)) << 17);
    }
  }
}

// Pass D: per-bucket (node,chunk) histogram -> ip2/dis, then chunk-ordered scatter.
// ip2[node*NCH+c] = start of node's chunk-c run; agg walks [ip2[w*8], ip2[w*8+8]).
__global__ __launch_bounds__(256) void build_kernel(const uint* __restrict__ binned,
                                                    const int* __restrict__ bucketBase,
                                                    int* __restrict__ ip2,
                                                    float* __restrict__ dis,
                                                    int* __restrict__ csr,
                                                    int n, int E, int nbuk) {
  __shared__ int h[BUK_NODES * NCH];
  __shared__ int off[BUK_NODES * NCH];
  __shared__ int ps[256];
  const int tid = threadIdx.x;
  const int b = blockIdx.x;
  const int lo = bucketBase[b], hi = bucketBase[b + 1];
#pragma unroll
  for (int k = tid; k < BUK_NODES * NCH; k += 256) h[k] = 0;
  __syncthreads();
  for (int i = lo + tid; i < hi; i += 256) {
    uint u = binned[i];
    int key = (int)((u >> 17) << 3) | (int)((u & 0x1FFFFu) >> 14);
    atomicAdd(&h[key], 1);
  }
  __syncthreads();
  // exclusive scan over 4096 entries: 16 serial per thread + block scan
  const int b16 = tid * 16;
  int loc[16];
  int s = 0;
#pragma unroll
  for (int j = 0; j < 16; ++j) {
    loc[j] = s;
    s += h[b16 + j];
  }
  ps[tid] = s;
  __syncthreads();
  for (int o = 1; o < 256; o <<= 1) {
    int t = 0;
    if (tid >= o) t = ps[tid - o];
    __syncthreads();
    ps[tid] += t;
    __syncthreads();
  }
  const int excl = ps[tid] - s;
#pragma unroll
  for (int j = 0; j < 16; ++j) off[b16 + j] = excl + loc[j];
  __syncthreads();
  const int node0 = b << BUK_SHIFT;
  for (int k = tid; k < BUK_NODES; k += 256) {
    int node = node0 + k;
    if (node < n) {
      int deg = 0;
#pragma unroll
      for (int c = 0; c < NCH; ++c) deg += h[k * NCH + c];
      dis[node] = rsqrtf((float)(deg + 1));
#pragma unroll
      for (int c = 0; c < NCH; ++c) ip2[(size_t)node * NCH + c] = lo + off[k * NCH + c];
    }
  }
  __syncthreads();
  for (int i = lo + tid; i < hi; i += 256) {
    uint u = binned[i];
    int key = (int)((u >> 17) << 3) | (int)((u & 0x1FFFFu) >> 14);
    int s2 = (int)(u & 0x1FFFFu);
    int r = atomicAdd(&off[key], 1);
    csr[lo + r] = s2;
  }
  if (b == nbuk - 1 && tid == 0) ip2[(size_t)n * NCH] = E;
}

// ---------------- W preconvert (both layers, one dispatch) ----------------
// Fragment slot (kc,j,lane) holds 8 bf16: W[kc*32 + (lane>>4)*8 + i][j*16 + (lane&15)]

__global__ __launch_bounds__(256) void wconv_kernel(const float* __restrict__ W1,
                                                    const float* __restrict__ W2,
                                                    ushort* __restrict__ Whi1,
                                                    ushort* __restrict__ Wlo1,
                                                    ushort* __restrict__ Whi2,
                                                    ushort* __restrict__ Wlo2) {
  const int g = blockIdx.x;  // 0..15
  const float* W = (g < 8) ? W1 : W2;
  ushort* Whi = (g < 8) ? Whi1 : Whi2;
  ushort* Wlo = (g < 8) ? Wlo1 : Wlo2;
  int slot = (g & 7) * 256 + threadIdx.x;
  int lane = slot & 63;
  int j = (slot >> 6) & 7;
  int kc = slot >> 9;
  ushort hb[8], lb[8];
#pragma unroll
  for (int i = 0; i < 8; ++i) {
    int k = kc * 32 + ((lane >> 4) << 3) + i;
    int c = j * 16 + (lane & 15);
    float f = W[k * 128 + c];
    uint hi = bf16rne(f);
    float hif = __uint_as_float(hi << 16);
    uint lo = __float_as_uint(f - hif) >> 16;
    hb[i] = (ushort)hi;
    lb[i] = (ushort)lo;
  }
  *reinterpret_cast<uint4*>(Whi + (size_t)slot * 8) = *reinterpret_cast<uint4*>(hb);
  *reinterpret_cast<uint4*>(Wlo + (size_t)slot * 8) = *reinterpret_cast<uint4*>(lb);
}

// ---------------- GEMM via split MFMA ----------------
// ABF16=false: A is f32, bf16x3 split (3 MFMA). ABF16=true: A already bf16 (2 MFMA).

template <bool ABF16>
__global__ __launch_bounds__(256) void gemm_mfma(const void* __restrict__ Ain,
                                                 const ushort* __restrict__ Whi,
                                                 const ushort* __restrict__ Wlo,
                                                 const float* __restrict__ scale,
                                                 uint* __restrict__ Cb, int n) {
  const int tid = threadIdx.x;
  const int wave = tid >> 6, lane = tid & 63;
  const int row = blockIdx.x * 64 + wave * 16 + (lane & 15);
  const int kgrp = lane >> 4;  // 0..3
  const bool rowok = row < n;

  f32x4 acc[8];
#pragma unroll
  for (int j = 0; j < 8; ++j) acc[j] = (f32x4){0.f, 0.f, 0.f, 0.f};

#pragma unroll
  for (int kc = 0; kc < 4; ++kc) {
    short8v ahi, alo;
    if constexpr (ABF16) {
      if (rowok) {
        ahi = *reinterpret_cast<const short8v*>(
            (const ushort*)Ain + (size_t)row * 128 + kc * 32 + kgrp * 8);
      } else {
#pragma unroll
        for (int i = 0; i < 8; ++i) ahi[i] = 0;
      }
    } else {
      const float* ap = (const float*)Ain + (size_t)row * 128 + kc * 32 + kgrp * 8;
      float4 a0 = make_float4(0.f, 0.f, 0.f, 0.f), a1 = a0;
      if (rowok) {
        a0 = *reinterpret_cast<const float4*>(ap);
        a1 = *reinterpret_cast<const float4*>(ap + 4);
      }
#pragma unroll
      for (int i = 0; i < 8; ++i) {
        float f = (i < 4) ? (&a0.x)[i] : (&a1.x)[i - 4];
        uint hi = bf16rne(f);
        float hif = __uint_as_float(hi << 16);
        uint lo = __float_as_uint(f - hif) >> 16;
        ahi[i] = (short)hi;
        alo[i] = (short)lo;
      }
    }
#pragma unroll
    for (int j = 0; j < 8; ++j) {
      const size_t base = ((size_t)(kc * 8 + j) * 64 + lane) * 8;
      short8v whi = *reinterpret_cast<const short8v*>(Whi + base);
      short8v wlo = *reinterpret_cast<const short8v*>(Wlo + base);
      acc[j] = __builtin_amdgcn_mfma_f32_16x16x32_bf16(whi, ahi, acc[j], 0, 0, 0);
      if constexpr (!ABF16)
        acc[j] = __builtin_amdgcn_mfma_f32_16x16x32_bf16(whi, alo, acc[j], 0, 0, 0);
      acc[j] = __builtin_amdgcn_mfma_f32_16x16x32_bf16(wlo, ahi, acc[j], 0, 0, 0);
    }
  }

  if (rowok) {
    const float s = scale[row];
#pragma unroll
    for (int j = 0; j < 8; ++j) {
      uint u0 = bf16rne(acc[j][0] * s) | (bf16rne(acc[j][1] * s) << 16);
      uint u1 = bf16rne(acc[j][2] * s) | (bf16rne(acc[j][3] * s) << 16);
      *reinterpret_cast<uint2*>(Cb + (size_t)row * 64 + j * 8 + kgrp * 2) =
          make_uint2(u0, u1);
    }
  }
}

// ---------------- aggregation ----------------
// O[i] = bf16( relu( dis[i]*( sum_{e} T'[src] + T'[i] ) + b ) ), chunk-ordered edges.

__global__ __launch_bounds__(256) void agg_kernel(const uint* __restrict__ T,
                                                  const int* __restrict__ ip2,
                                                  const int* __restrict__ csr,
                                                  const float* __restrict__ dis,
                                                  const float* __restrict__ bias,
                                                  uint* __restrict__ O, int n) {
  int wid = (blockIdx.x << 2) + (threadIdx.x >> 6);  // one wave per node
  if (wid >= n) return;
  wid = __builtin_amdgcn_readfirstlane(wid);
  const int lane = threadIdx.x & 63;
  const int e0 = ip2[(size_t)wid * NCH];
  const int e1 = ip2[(size_t)wid * NCH + NCH];
  float ax = 0.f, ay = 0.f;
#define TLOAD(s) T[(size_t)(s) * 64 + lane]
  int e = e0;
  for (; e + 8 <= e1; e += 8) {
    int s0 = csr[e], s1 = csr[e + 1], s2 = csr[e + 2], s3 = csr[e + 3];
    int s4 = csr[e + 4], s5 = csr[e + 5], s6 = csr[e + 6], s7 = csr[e + 7];
    uint u0 = TLOAD(s0), u1 = TLOAD(s1), u2 = TLOAD(s2), u3 = TLOAD(s3);
    uint u4 = TLOAD(s4), u5 = TLOAD(s5), u6 = TLOAD(s6), u7 = TLOAD(s7);
    ax += ((blo(u0) + blo(u1)) + (blo(u2) + blo(u3))) +
          ((blo(u4) + blo(u5)) + (blo(u6) + blo(u7)));
    ay += ((bhi(u0) + bhi(u1)) + (bhi(u2) + bhi(u3))) +
          ((bhi(u4) + bhi(u5)) + (bhi(u6) + bhi(u7)));
  }
  for (; e + 4 <= e1; e += 4) {
    int s0 = csr[e], s1 = csr[e + 1], s2 = csr[e + 2], s3 = csr[e + 3];
    uint u0 = TLOAD(s0), u1 = TLOAD(s1), u2 = TLOAD(s2), u3 = TLOAD(s3);
    ax += (blo(u0) + blo(u1)) + (blo(u2) + blo(u3));
    ay += (bhi(u0) + bhi(u1)) + (bhi(u2) + bhi(u3));
  }
  for (; e < e1; ++e) {
    uint u = TLOAD(csr[e]);
    ax += blo(u);
    ay += bhi(u);
  }
  uint us = TLOAD(wid);  // self loop
  ax += blo(us);
  ay += bhi(us);
  const float di = dis[wid];
  const float2 b = *reinterpret_cast<const float2*>(bias + lane * 2);
  float ox = fmaxf(fmaf(di, ax, b.x), 0.f);
  float oy = fmaxf(fmaf(di, ay, b.y), 0.f);
  O[(size_t)wid * 64 + lane] = bf16rne(ox) | (bf16rne(oy) << 16);
}

// ---------------- pooling over sorted batch ids (bf16 input) ----------------

__global__ __launch_bounds__(256) void pool_kernel(const uint* __restrict__ H,
                                                   const int* __restrict__ batch,
                                                   float* __restrict__ pooled,
                                                   float* __restrict__ cntg, int n) {
  __shared__ float sd[256 * 4];
  const int tid = threadIdx.x;
  const int c4 = (tid & 31) << 2;  // column base (4 cols = 2 uints)
  const int rs = tid >> 5;         // 0..7 row subgroup
  const int base = blockIdx.x * PCHUNK;
  const int lim = min(base + PCHUNK, n);
  const int g0 = batch[base];
  const int gN = batch[lim - 1];
  float4 acc = make_float4(0.f, 0.f, 0.f, 0.f);
  if (g0 == gN) {
    for (int r = base + rs; r < lim; r += 8) {
      uint2 v = *reinterpret_cast<const uint2*>(H + (size_t)r * 64 + (c4 >> 1));
      acc.x += blo(v.x); acc.y += bhi(v.x); acc.z += blo(v.y); acc.w += bhi(v.y);
    }
    *reinterpret_cast<float4*>(&sd[tid * 4]) = acc;
    __syncthreads();
    if (tid < 128) {
      float4 o = *reinterpret_cast<float4*>(&sd[(tid + 128) * 4]);
      acc.x += o.x; acc.y += o.y; acc.z += o.z; acc.w += o.w;
      *reinterpret_cast<float4*>(&sd[tid * 4]) = acc;
    }
    __syncthreads();
    if (tid < 64) {
      float4 o = *reinterpret_cast<float4*>(&sd[(tid + 64) * 4]);
      acc.x += o.x; acc.y += o.y; acc.z += o.z; acc.w += o.w;
      *reinterpret_cast<float4*>(&sd[tid * 4]) = acc;
    }
    __syncthreads();
    if (tid < 32) {
      float4 o = *reinterpret_cast<float4*>(&sd[(tid + 32) * 4]);
      acc.x += o.x; acc.y += o.y; acc.z += o.z; acc.w += o.w;
      atomicAdd(&pooled[g0 * 128 + c4 + 0], acc.x);
      atomicAdd(&pooled[g0 * 128 + c4 + 1], acc.y);
      atomicAdd(&pooled[g0 * 128 + c4 + 2], acc.z);
      atomicAdd(&pooled[g0 * 128 + c4 + 3], acc.w);
      if (tid == 0) atomicAdd(&cntg[g0], (float)(lim - base));
    }
  } else {
    int curg = -1, cnt = 0;
    for (int r = base + rs; r < lim; r += 8) {
      int g = batch[r];
      if (g != curg) {
        if (curg >= 0) {
          atomicAdd(&pooled[curg * 128 + c4 + 0], acc.x);
          atomicAdd(&pooled[curg * 128 + c4 + 1], acc.y);
          atomicAdd(&pooled[curg * 128 + c4 + 2], acc.z);
          atomicAdd(&pooled[curg * 128 + c4 + 3], acc.w);
          if ((tid & 31) == 0) atomicAdd(&cntg[curg], (float)cnt);
        }
        curg = g;
        acc = make_float4(0.f, 0.f, 0.f, 0.f);
        cnt = 0;
      }
      uint2 v = *reinterpret_cast<const uint2*>(H + (size_t)r * 64 + (c4 >> 1));
      acc.x += blo(v.x); acc.y += bhi(v.x); acc.z += blo(v.y); acc.w += bhi(v.y);
      cnt++;
    }
    if (curg >= 0) {
      atomicAdd(&pooled[curg * 128 + c4 + 0], acc.x);
      atomicAdd(&pooled[curg * 128 + c4 + 1], acc.y);
      atomicAdd(&pooled[curg * 128 + c4 + 2], acc.z);
      atomicAdd(&pooled[curg * 128 + c4 + 3], acc.w);
      if ((tid & 31) == 0) atomicAdd(&cntg[curg], (float)cnt);
    }
  }
}

__global__ __launch_bounds__(128) void final_kernel(const float* __restrict__ pooled,
                                                    const float* __restrict__ cntg,
                                                    const float* __restrict__ Wp,
                                                    const float* __restrict__ bp,
                                                    float* __restrict__ out) {
  const int g = blockIdx.x;
  const int e = threadIdx.x;
  float inv = 1.0f / fmaxf(cntg[g], 1.0f);
  float acc = 0.f;
  for (int c = 0; c < 128; ++c)
    acc = fmaf(pooled[g * 128 + c], Wp[c * 128 + e], acc);
  out[g * 128 + e] = acc * inv + bp[e];
}

// ---------------- launch ----------------

extern "C" void kernel_launch(void* const* d_in, const int* in_sizes, int n_in,
                              void* d_out, int out_size, void* d_ws, size_t ws_size,
                              hipStream_t stream) {
  const float* x = (const float*)d_in[0];
  const int* eidx = (const int*)d_in[1];
  const int* batch = (const int*)d_in[2];
  const float* W1 = (const float*)d_in[3];
  const float* b1 = (const float*)d_in[4];
  const float* W2 = (const float*)d_in[5];
  const float* b2 = (const float*)d_in[6];
  const float* Wp = (const float*)d_in[7];
  const float* bp = (const float*)d_in[8];

  const int n = in_sizes[0] / 128;
  const int E = in_sizes[1] / 2;
  const int* row = eidx;      // edge_index[0] = sources
  const int* col = eidx + E;  // edge_index[1] = targets
  const int nbuk = (n + BUK_NODES - 1) >> BUK_SHIFT;

  char* ws = (char*)d_ws;
  size_t off = 0;
  auto alloc = [&](size_t bytes) {
    void* p = ws + off;
    off = (off + bytes + 255) & ~(size_t)255;
    return p;
  };
  uint* Tb = (uint*)alloc((size_t)n * 64 * 4);   // bf16-packed messages
  uint* Bb = (uint*)alloc((size_t)n * 64 * 4);   // bf16-packed hidden state
  float* dis = (float*)alloc((size_t)n * 4);
  int* ip2 = (int*)alloc(((size_t)n * NCH + 1) * 4);
  int* csr = (int*)alloc((size_t)E * 4);
  uint* binned = (uint*)alloc((size_t)E * 4);
  int* bucketBase = (int*)alloc(257 * 4);
  // contiguous zero region: ghist(256) | cntg(64) | pooled(GG*128)
  int* zbase = (int*)alloc((256 + 64 + GG * 128) * 4);
  int* ghist = zbase;
  float* cntg = (float*)(zbase + 256);
  float* pooled = (float*)(zbase + 256 + 64);
  int* gcur = (int*)alloc(256 * 4);
  ushort* Whi1 = (ushort*)alloc(2048 * 8 * 2);
  ushort* Wlo1 = (ushort*)alloc(2048 * 8 * 2);
  ushort* Whi2 = (ushort*)alloc(2048 * 8 * 2);
  ushort* Wlo2 = (ushort*)alloc(2048 * 8 * 2);
  (void)off;

  hipMemsetAsync(zbase, 0, (256 + 64 + GG * 128) * 4, stream);

  const int eblocks = (E + EPB - 1) / EPB;
  hist_kernel<<<eblocks, 256, 0, stream>>>(col, ghist, E, nbuk);
  scan_kernel<<<1, 256, 0, stream>>>(ghist, bucketBase, gcur, nbuk, E);
  bin_kernel<<<eblocks, 256, 0, stream>>>(row, col, gcur, binned, E);
  build_kernel<<<nbuk, 256, 0, stream>>>(binned, bucketBase, ip2, dis, csr, n, E, nbuk);
  wconv_kernel<<<16, 256, 0, stream>>>(W1, W2, Whi1, Wlo1, Whi2, Wlo2);

  const int gblocks = (n + 63) / 64;
  gemm_mfma<false><<<gblocks, 256, 0, stream>>>(x, Whi1, Wlo1, dis, Tb, n);
  agg_kernel<<<(n + 3) / 4, 256, 0, stream>>>(Tb, ip2, csr, dis, b1, Bb, n);
  gemm_mfma<true><<<gblocks, 256, 0, stream>>>(Bb, Whi2, Wlo2, dis, Tb, n);
  agg_kernel<<<(n + 3) / 4, 256, 0, stream>>>(Tb, ip2, csr, dis, b2, Bb, n);

  pool_kernel<<<(n + PCHUNK - 1) / PCHUNK, 256, 0, stream>>>(Bb, batch, pooled, cntg, n);
  final_kernel<<<GG, 128, 0, stream>>>(pooled, cntg, Wp, bp, (float*)d_out);
}

// Round 7
// 258.878 us; speedup vs baseline: 22.3154x; 1.0464x over previous
//
#include <hip/hip_runtime.h>
#include <cstdint>
#include <cstddef>

#define GG 64
#define EPB 4096        // edges per block in bin
#define BUK_SHIFT 9
#define BUK_NODES 512   // nodes per bucket
#define BCAP 16384      // fixed bucket capacity (mean 8192, +90 sigma)
#define PCHUNK 64       // rows per pool block
#define NCH 8           // source chunks (src>>14) for gather locality ordering

typedef unsigned int uint;
typedef unsigned short ushort;
typedef __attribute__((ext_vector_type(8))) short short8v;  // 8 bf16 (4 VGPRs)
typedef __attribute__((ext_vector_type(4))) float f32x4;

__device__ __forceinline__ float blo(uint u) { return __uint_as_float(u << 16); }
__device__ __forceinline__ float bhi(uint u) { return __uint_as_float(u & 0xffff0000u); }

__device__ __forceinline__ uint bf16rne(float f) {
  uint u = __float_as_uint(f);
  return (u + 0x7fffu + ((u >> 16) & 1u)) >> 16;
}

// ---------------- CSR build: fixed-capacity two-level counting sort ----------------

__global__ __launch_bounds__(256) void initcur_kernel(int* __restrict__ gcur) {
  gcur[threadIdx.x] = threadIdx.x * BCAP;
}

// Bin edges by 512-node bucket into fixed-capacity regions.
// Packed entry: src | (dst&511)<<17 (needs n < 2^17).
__global__ __launch_bounds__(256) void bin_kernel(const int* __restrict__ row,
                                                  const int* __restrict__ col,
                                                  int* __restrict__ gcur,
                                                  uint* __restrict__ binned, int E) {
  __shared__ int h[256];
  __shared__ int bbase[256];
  __shared__ int lcur[256];
  const int tid = threadIdx.x;
  const int base = blockIdx.x * EPB;
  int src[EPB / 256];
  int dst[EPB / 256];
#pragma unroll
  for (int j = 0; j < EPB / 256; ++j) {
    int e = base + j * 256 + tid;
    if (e < E) {
      src[j] = row[e];
      dst[j] = col[e];
    } else {
      dst[j] = -1;
    }
  }
  h[tid] = 0;
  lcur[tid] = 0;
  __syncthreads();
#pragma unroll
  for (int j = 0; j < EPB / 256; ++j)
    if (dst[j] >= 0) atomicAdd(&h[dst[j] >> BUK_SHIFT], 1);
  __syncthreads();
  if (h[tid] > 0) bbase[tid] = atomicAdd(&gcur[tid], h[tid]);
  __syncthreads();
#pragma unroll
  for (int j = 0; j < EPB / 256; ++j) {
    if (dst[j] >= 0) {
      int b = dst[j] >> BUK_SHIFT;
      int r = atomicAdd(&lcur[b], 1);
      int pos = bbase[b] + r;
      if (pos < ((b + 1) * BCAP))  // overflow drop-guard (never fires at 90 sigma)
        binned[pos] = (uint)src[j] | ((uint)(dst[j] & (BUK_NODES - 1)) << 17);
    }
  }
}

// Per-bucket (node,chunk) histogram -> ndesc/dis, then chunk-ordered scatter to csr.
__global__ __launch_bounds__(256) void build_kernel(const uint* __restrict__ binned,
                                                    const int* __restrict__ gcur,
                                                    int2* __restrict__ ndesc,
                                                    float* __restrict__ dis,
                                                    int* __restrict__ csr, int n) {
  __shared__ int h[BUK_NODES * NCH];
  __shared__ int off[BUK_NODES * NCH];
  __shared__ int ps[256];
  const int tid = threadIdx.x;
  const int b = blockIdx.x;
  const int lo = b * BCAP;
  const int hi = min(gcur[b], lo + BCAP);
#pragma unroll
  for (int k = tid; k < BUK_NODES * NCH; k += 256) h[k] = 0;
  __syncthreads();
  for (int i = lo + tid; i < hi; i += 256) {
    uint u = binned[i];
    int key = (int)((u >> 17) << 3) | (int)((u & 0x1FFFFu) >> 14);
    atomicAdd(&h[key], 1);
  }
  __syncthreads();
  // exclusive scan over 4096 entries: 16 serial per thread + block scan
  const int b16 = tid * 16;
  int loc[16];
  int s = 0;
#pragma unroll
  for (int j = 0; j < 16; ++j) {
    loc[j] = s;
    s += h[b16 + j];
  }
  ps[tid] = s;
  __syncthreads();
  for (int o = 1; o < 256; o <<= 1) {
    int t = 0;
    if (tid >= o) t = ps[tid - o];
    __syncthreads();
    ps[tid] += t;
    __syncthreads();
  }
  const int excl = ps[tid] - s;
#pragma unroll
  for (int j = 0; j < 16; ++j) off[b16 + j] = excl + loc[j];
  __syncthreads();
  const int node0 = b << BUK_SHIFT;
  for (int k = tid; k < BUK_NODES; k += 256) {
    int node = node0 + k;
    if (node < n) {
      int deg = 0;
#pragma unroll
      for (int c = 0; c < NCH; ++c) deg += h[k * NCH + c];
      dis[node] = rsqrtf((float)(deg + 1));
      int e0 = lo + off[k * NCH];
      int e1 = (k == BUK_NODES - 1) ? hi : lo + off[(k + 1) * NCH];
      ndesc[node] = make_int2(e0, e1);
    }
  }
  __syncthreads();
  for (int i = lo + tid; i < hi; i += 256) {
    uint u = binned[i];
    int key = (int)((u >> 17) << 3) | (int)((u & 0x1FFFFu) >> 14);
    int s2 = (int)(u & 0x1FFFFu);
    int r = atomicAdd(&off[key], 1);
    csr[lo + r] = s2;
  }
}

// ---------------- W preconvert (both layers, one dispatch) ----------------
// Fragment slot (kc,j,lane) holds 8 bf16: W[kc*32 + (lane>>4)*8 + i][j*16 + (lane&15)]

__global__ __launch_bounds__(256) void wconv_kernel(const float* __restrict__ W1,
                                                    const float* __restrict__ W2,
                                                    ushort* __restrict__ Whi1,
                                                    ushort* __restrict__ Wlo1,
                                                    ushort* __restrict__ Whi2,
                                                    ushort* __restrict__ Wlo2) {
  const int g = blockIdx.x;  // 0..15
  const float* W = (g < 8) ? W1 : W2;
  ushort* Whi = (g < 8) ? Whi1 : Whi2;
  ushort* Wlo = (g < 8) ? Wlo1 : Wlo2;
  int slot = (g & 7) * 256 + threadIdx.x;
  int lane = slot & 63;
  int j = (slot >> 6) & 7;
  int kc = slot >> 9;
  ushort hb[8], lb[8];
#pragma unroll
  for (int i = 0; i < 8; ++i) {
    int k = kc * 32 + ((lane >> 4) << 3) + i;
    int c = j * 16 + (lane & 15);
    float f = W[k * 128 + c];
    uint hi = bf16rne(f);
    float hif = __uint_as_float(hi << 16);
    uint lo = __float_as_uint(f - hif) >> 16;
    hb[i] = (ushort)hi;
    lb[i] = (ushort)lo;
  }
  *reinterpret_cast<uint4*>(Whi + (size_t)slot * 8) = *reinterpret_cast<uint4*>(hb);
  *reinterpret_cast<uint4*>(Wlo + (size_t)slot * 8) = *reinterpret_cast<uint4*>(lb);
}

// ---------------- GEMM via split MFMA ----------------
// ABF16=false: A is f32, bf16x3 split (3 MFMA). ABF16=true: A already bf16 (2 MFMA).

template <bool ABF16>
__global__ __launch_bounds__(256) void gemm_mfma(const void* __restrict__ Ain,
                                                 const ushort* __restrict__ Whi,
                                                 const ushort* __restrict__ Wlo,
                                                 const float* __restrict__ scale,
                                                 uint* __restrict__ Cb, int n) {
  const int tid = threadIdx.x;
  const int wave = tid >> 6, lane = tid & 63;
  const int row = blockIdx.x * 64 + wave * 16 + (lane & 15);
  const int kgrp = lane >> 4;  // 0..3
  const bool rowok = row < n;

  f32x4 acc[8];
#pragma unroll
  for (int j = 0; j < 8; ++j) acc[j] = (f32x4){0.f, 0.f, 0.f, 0.f};

#pragma unroll
  for (int kc = 0; kc < 4; ++kc) {
    short8v ahi, alo;
    if constexpr (ABF16) {
      if (rowok) {
        ahi = *reinterpret_cast<const short8v*>(
            (const ushort*)Ain + (size_t)row * 128 + kc * 32 + kgrp * 8);
      } else {
#pragma unroll
        for (int i = 0; i < 8; ++i) ahi[i] = 0;
      }
    } else {
      const float* ap = (const float*)Ain + (size_t)row * 128 + kc * 32 + kgrp * 8;
      float4 a0 = make_float4(0.f, 0.f, 0.f, 0.f), a1 = a0;
      if (rowok) {
        a0 = *reinterpret_cast<const float4*>(ap);
        a1 = *reinterpret_cast<const float4*>(ap + 4);
      }
#pragma unroll
      for (int i = 0; i < 8; ++i) {
        float f = (i < 4) ? (&a0.x)[i] : (&a1.x)[i - 4];
        uint hi = bf16rne(f);
        float hif = __uint_as_float(hi << 16);
        uint lo = __float_as_uint(f - hif) >> 16;
        ahi[i] = (short)hi;
        alo[i] = (short)lo;
      }
    }
#pragma unroll
    for (int j = 0; j < 8; ++j) {
      const size_t base = ((size_t)(kc * 8 + j) * 64 + lane) * 8;
      short8v whi = *reinterpret_cast<const short8v*>(Whi + base);
      short8v wlo = *reinterpret_cast<const short8v*>(Wlo + base);
      acc[j] = __builtin_amdgcn_mfma_f32_16x16x32_bf16(whi, ahi, acc[j], 0, 0, 0);
      if constexpr (!ABF16)
        acc[j] = __builtin_amdgcn_mfma_f32_16x16x32_bf16(whi, alo, acc[j], 0, 0, 0);
      acc[j] = __builtin_amdgcn_mfma_f32_16x16x32_bf16(wlo, ahi, acc[j], 0, 0, 0);
    }
  }

  if (rowok) {
    const float s = scale[row];
#pragma unroll
    for (int j = 0; j < 8; ++j) {
      uint u0 = bf16rne(acc[j][0] * s) | (bf16rne(acc[j][1] * s) << 16);
      uint u1 = bf16rne(acc[j][2] * s) | (bf16rne(acc[j][3] * s) << 16);
      *reinterpret_cast<uint2*>(Cb + (size_t)row * 64 + j * 8 + kgrp * 2) =
          make_uint2(u0, u1);
    }
  }
}

// ---------------- aggregation ----------------
// O[i] = bf16( relu( dis[i]*( sum_{e} T'[src] + T'[i] ) + b ) )
// Cooperative csr load (1 coalesced vector load per <=64 edges) + shfl broadcast;
// gathers issued in 16-deep batches -> ~3 memory latencies per node.

__global__ __launch_bounds__(256) void agg_kernel(const uint* __restrict__ T,
                                                  const int2* __restrict__ ndesc,
                                                  const int* __restrict__ csr,
                                                  const float* __restrict__ dis,
                                                  const float* __restrict__ bias,
                                                  uint* __restrict__ O, int n) {
  int wid = (blockIdx.x << 2) + (threadIdx.x >> 6);  // one wave per node
  if (wid >= n) return;
  wid = __builtin_amdgcn_readfirstlane(wid);
  const int lane = threadIdx.x & 63;
  const uint* Tl = T + lane;
  const int2 dd = ndesc[wid];             // uniform 8B load
  const uint us = Tl[(size_t)wid * 64];   // self loop, issued early
  const float di = dis[wid];
  const float2 bb = *reinterpret_cast<const float2*>(bias + lane * 2);

  float ax0 = 0.f, ay0 = 0.f, ax1 = 0.f, ay1 = 0.f;
  float ax2 = 0.f, ay2 = 0.f, ax3 = 0.f, ay3 = 0.f;

  for (int base = dd.x; base < dd.y; base += 64) {
    const int cn = min(64, dd.y - base);  // uniform
    const int sv = (lane < cn) ? csr[base + lane] : 0;  // coalesced
    int e = 0;
    for (; e + 16 <= cn; e += 16) {
      uint g[16];
#pragma unroll
      for (int k = 0; k < 16; ++k) {
        int s = __shfl(sv, e + k, 64);
        g[k] = Tl[(size_t)s * 64];
      }
#pragma unroll
      for (int k = 0; k < 16; k += 4) {
        ax0 += blo(g[k]);     ay0 += bhi(g[k]);
        ax1 += blo(g[k + 1]); ay1 += bhi(g[k + 1]);
        ax2 += blo(g[k + 2]); ay2 += bhi(g[k + 2]);
        ax3 += blo(g[k + 3]); ay3 += bhi(g[k + 3]);
      }
    }
    for (; e + 4 <= cn; e += 4) {
      int s0 = __shfl(sv, e, 64), s1 = __shfl(sv, e + 1, 64);
      int s2 = __shfl(sv, e + 2, 64), s3 = __shfl(sv, e + 3, 64);
      uint g0 = Tl[(size_t)s0 * 64], g1 = Tl[(size_t)s1 * 64];
      uint g2 = Tl[(size_t)s2 * 64], g3 = Tl[(size_t)s3 * 64];
      ax0 += blo(g0); ay0 += bhi(g0);
      ax1 += blo(g1); ay1 += bhi(g1);
      ax2 += blo(g2); ay2 += bhi(g2);
      ax3 += blo(g3); ay3 += bhi(g3);
    }
    for (; e < cn; ++e) {
      int s = __shfl(sv, e, 64);
      uint g = Tl[(size_t)s * 64];
      ax0 += blo(g);
      ay0 += bhi(g);
    }
  }
  float ax = (ax0 + ax1) + (ax2 + ax3) + blo(us);
  float ay = (ay0 + ay1) + (ay2 + ay3) + bhi(us);
  float ox = fmaxf(fmaf(di, ax, bb.x), 0.f);
  float oy = fmaxf(fmaf(di, ay, bb.y), 0.f);
  O[(size_t)wid * 64 + lane] = bf16rne(ox) | (bf16rne(oy) << 16);
}

// ---------------- pooling over sorted batch ids (bf16 input) ----------------

__global__ __launch_bounds__(256) void pool_kernel(const uint* __restrict__ H,
                                                   const int* __restrict__ batch,
                                                   float* __restrict__ pooled,
                                                   float* __restrict__ cntg, int n) {
  __shared__ float sd[256 * 4];
  const int tid = threadIdx.x;
  const int c4 = (tid & 31) << 2;  // column base (4 cols = 2 uints)
  const int rs = tid >> 5;         // 0..7 row subgroup
  const int base = blockIdx.x * PCHUNK;
  const int lim = min(base + PCHUNK, n);
  const int g0 = batch[base];
  const int gN = batch[lim - 1];
  float4 acc = make_float4(0.f, 0.f, 0.f, 0.f);
  if (g0 == gN) {
    for (int r = base + rs; r < lim; r += 8) {
      uint2 v = *reinterpret_cast<const uint2*>(H + (size_t)r * 64 + (c4 >> 1));
      acc.x += blo(v.x); acc.y += bhi(v.x); acc.z += blo(v.y); acc.w += bhi(v.y);
    }
    *reinterpret_cast<float4*>(&sd[tid * 4]) = acc;
    __syncthreads();
    if (tid < 128) {
      float4 o = *reinterpret_cast<float4*>(&sd[(tid + 128) * 4]);
      acc.x += o.x; acc.y += o.y; acc.z += o.z; acc.w += o.w;
      *reinterpret_cast<float4*>(&sd[tid * 4]) = acc;
    }
    __syncthreads();
    if (tid < 64) {
      float4 o = *reinterpret_cast<float4*>(&sd[(tid + 64) * 4]);
      acc.x += o.x; acc.y += o.y; acc.z += o.z; acc.w += o.w;
      *reinterpret_cast<float4*>(&sd[tid * 4]) = acc;
    }
    __syncthreads();
    if (tid < 32) {
      float4 o = *reinterpret_cast<float4*>(&sd[(tid + 32) * 4]);
      acc.x += o.x; acc.y += o.y; acc.z += o.z; acc.w += o.w;
      atomicAdd(&pooled[g0 * 128 + c4 + 0], acc.x);
      atomicAdd(&pooled[g0 * 128 + c4 + 1], acc.y);
      atomicAdd(&pooled[g0 * 128 + c4 + 2], acc.z);
      atomicAdd(&pooled[g0 * 128 + c4 + 3], acc.w);
      if (tid == 0) atomicAdd(&cntg[g0], (float)(lim - base));
    }
  } else {
    int curg = -1, cnt = 0;
    for (int r = base + rs; r < lim; r += 8) {
      int g = batch[r];
      if (g != curg) {
        if (curg >= 0) {
          atomicAdd(&pooled[curg * 128 + c4 + 0], acc.x);
          atomicAdd(&pooled[curg * 128 + c4 + 1], acc.y);
          atomicAdd(&pooled[curg * 128 + c4 + 2], acc.z);
          atomicAdd(&pooled[curg * 128 + c4 + 3], acc.w);
          if ((tid & 31) == 0) atomicAdd(&cntg[curg], (float)cnt);
        }
        curg = g;
        acc = make_float4(0.f, 0.f, 0.f, 0.f);
        cnt = 0;
      }
      uint2 v = *reinterpret_cast<const uint2*>(H + (size_t)r * 64 + (c4 >> 1));
      acc.x += blo(v.x); acc.y += bhi(v.x); acc.z += blo(v.y); acc.w += bhi(v.y);
      cnt++;
    }
    if (curg >= 0) {
      atomicAdd(&pooled[curg * 128 + c4 + 0], acc.x);
      atomicAdd(&pooled[curg * 128 + c4 + 1], acc.y);
      atomicAdd(&pooled[curg * 128 + c4 + 2], acc.z);
      atomicAdd(&pooled[curg * 128 + c4 + 3], acc.w);
      if ((tid & 31) == 0) atomicAdd(&cntg[curg], (float)cnt);
    }
  }
}

__global__ __launch_bounds__(128) void final_kernel(const float* __restrict__ pooled,
                                                    const float* __restrict__ cntg,
                                                    const float* __restrict__ Wp,
                                                    const float* __restrict__ bp,
                                                    float* __restrict__ out) {
  const int g = blockIdx.x;
  const int e = threadIdx.x;
  float inv = 1.0f / fmaxf(cntg[g], 1.0f);
  float acc = 0.f;
  for (int c = 0; c < 128; ++c)
    acc = fmaf(pooled[g * 128 + c], Wp[c * 128 + e], acc);
  out[g * 128 + e] = acc * inv + bp[e];
}

// ---------------- launch ----------------

extern "C" void kernel_launch(void* const* d_in, const int* in_sizes, int n_in,
                              void* d_out, int out_size, void* d_ws, size_t ws_size,
                              hipStream_t stream) {
  const float* x = (const float*)d_in[0];
  const int* eidx = (const int*)d_in[1];
  const int* batch = (const int*)d_in[2];
  const float* W1 = (const float*)d_in[3];
  const float* b1 = (const float*)d_in[4];
  const float* W2 = (const float*)d_in[5];
  const float* b2 = (const float*)d_in[6];
  const float* Wp = (const float*)d_in[7];
  const float* bp = (const float*)d_in[8];

  const int n = in_sizes[0] / 128;
  const int E = in_sizes[1] / 2;
  const int* row = eidx;      // edge_index[0] = sources
  const int* col = eidx + E;  // edge_index[1] = targets
  const int nbuk = (n + BUK_NODES - 1) >> BUK_SHIFT;

  char* ws = (char*)d_ws;
  size_t off = 0;
  auto alloc = [&](size_t bytes) {
    void* p = ws + off;
    off = (off + bytes + 255) & ~(size_t)255;
    return p;
  };
  uint* Tb = (uint*)alloc((size_t)n * 64 * 4);   // bf16-packed messages
  uint* Bb = (uint*)alloc((size_t)n * 64 * 4);   // bf16-packed hidden state
  float* dis = (float*)alloc((size_t)n * 4);
  int2* ndesc = (int2*)alloc((size_t)n * 8);
  int* csr = (int*)alloc((size_t)nbuk * BCAP * 4);
  uint* binned = (uint*)alloc((size_t)nbuk * BCAP * 4);
  int* gcur = (int*)alloc(256 * 4);
  // contiguous zero region: cntg(64) | pooled(GG*128)
  float* zbase = (float*)alloc((64 + GG * 128) * 4);
  float* cntg = zbase;
  float* pooled = zbase + 64;
  ushort* Whi1 = (ushort*)alloc(2048 * 8 * 2);
  ushort* Wlo1 = (ushort*)alloc(2048 * 8 * 2);
  ushort* Whi2 = (ushort*)alloc(2048 * 8 * 2);
  ushort* Wlo2 = (ushort*)alloc(2048 * 8 * 2);
  (void)off;

  hipMemsetAsync(zbase, 0, (64 + GG * 128) * 4, stream);
  initcur_kernel<<<1, 256, 0, stream>>>(gcur);

  const int eblocks = (E + EPB - 1) / EPB;
  bin_kernel<<<eblocks, 256, 0, stream>>>(row, col, gcur, binned, E);
  build_kernel<<<nbuk, 256, 0, stream>>>(binned, gcur, ndesc, dis, csr, n);
  wconv_kernel<<<16, 256, 0, stream>>>(W1, W2, Whi1, Wlo1, Whi2, Wlo2);

  const int gblocks = (n + 63) / 64;
  gemm_mfma<false><<<gblocks, 256, 0, stream>>>(x, Whi1, Wlo1, dis, Tb, n);
  agg_kernel<<<(n + 3) / 4, 256, 0, stream>>>(Tb, ndesc, csr, dis, b1, Bb, n);
  gemm_mfma<true><<<gblocks, 256, 0, stream>>>(Bb, Whi2, Wlo2, dis, Tb, n);
  agg_kernel<<<(n + 3) / 4, 256, 0, stream>>>(Tb, ndesc, csr, dis, b2, Bb, n);

  pool_kernel<<<(n + PCHUNK - 1) / PCHUNK, 256, 0, stream>>>(Bb, batch, pooled, cntg, n);
  final_kernel<<<GG, 128, 0, stream>>>(pooled, cntg, Wp, bp, (float*)d_out);
}

// Round 8
// 258.326 us; speedup vs baseline: 22.3631x; 1.0021x over previous
//
#include <hip/hip_runtime.h>
#include <cstdint>
#include <cstddef>

#define GG 64
#define EPB 4096        // edges per block in bin
#define BUK_SHIFT 9
#define BUK_NODES 512   // nodes per bucket
#define BCAP 16384      // fixed bucket capacity (mean 8192, +90 sigma)
#define PCHUNK 64       // rows per pool block
#define NCH 8           // source chunks (src>>14) for gather locality ordering

typedef unsigned int uint;
typedef unsigned short ushort;
typedef __attribute__((ext_vector_type(8))) short short8v;  // 8 bf16 (4 VGPRs)
typedef __attribute__((ext_vector_type(4))) float f32x4;

__device__ __forceinline__ float blo(uint u) { return __uint_as_float(u << 16); }
__device__ __forceinline__ float bhi(uint u) { return __uint_as_float(u & 0xffff0000u); }

__device__ __forceinline__ uint bf16rne(float f) {
  uint u = __float_as_uint(f);
  return (u + 0x7fffu + ((u >> 16) & 1u)) >> 16;
}

// ---------------- CSR build: fixed-capacity two-level counting sort ----------------

__global__ __launch_bounds__(256) void initcur_kernel(int* __restrict__ gcur) {
  gcur[threadIdx.x] = threadIdx.x * BCAP;
}

// Bin edges by 512-node bucket into fixed-capacity regions.
// Packed entry: src | (dst&511)<<17 (needs n < 2^17).
__global__ __launch_bounds__(256) void bin_kernel(const int* __restrict__ row,
                                                  const int* __restrict__ col,
                                                  int* __restrict__ gcur,
                                                  uint* __restrict__ binned, int E) {
  __shared__ int h[256];
  __shared__ int bbase[256];
  __shared__ int lcur[256];
  const int tid = threadIdx.x;
  const int base = blockIdx.x * EPB;
  int src[EPB / 256];
  int dst[EPB / 256];
#pragma unroll
  for (int j = 0; j < EPB / 256; ++j) {
    int e = base + j * 256 + tid;
    if (e < E) {
      src[j] = row[e];
      dst[j] = col[e];
    } else {
      dst[j] = -1;
    }
  }
  h[tid] = 0;
  lcur[tid] = 0;
  __syncthreads();
#pragma unroll
  for (int j = 0; j < EPB / 256; ++j)
    if (dst[j] >= 0) atomicAdd(&h[dst[j] >> BUK_SHIFT], 1);
  __syncthreads();
  if (h[tid] > 0) bbase[tid] = atomicAdd(&gcur[tid], h[tid]);
  __syncthreads();
#pragma unroll
  for (int j = 0; j < EPB / 256; ++j) {
    if (dst[j] >= 0) {
      int b = dst[j] >> BUK_SHIFT;
      int r = atomicAdd(&lcur[b], 1);
      int pos = bbase[b] + r;
      if (pos < ((b + 1) * BCAP))  // overflow drop-guard (never fires at 90 sigma)
        binned[pos] = (uint)src[j] | ((uint)(dst[j] & (BUK_NODES - 1)) << 17);
    }
  }
}

// Per-bucket (node,chunk) histogram -> ndesc/dis, then chunk-ordered scatter to csr.
__global__ __launch_bounds__(256) void build_kernel(const uint* __restrict__ binned,
                                                    const int* __restrict__ gcur,
                                                    int2* __restrict__ ndesc,
                                                    float* __restrict__ dis,
                                                    int* __restrict__ csr, int n) {
  __shared__ int h[BUK_NODES * NCH];
  __shared__ int off[BUK_NODES * NCH];
  __shared__ int ps[256];
  const int tid = threadIdx.x;
  const int b = blockIdx.x;
  const int lo = b * BCAP;
  const int hi = min(gcur[b], lo + BCAP);
#pragma unroll
  for (int k = tid; k < BUK_NODES * NCH; k += 256) h[k] = 0;
  __syncthreads();
  for (int i = lo + tid; i < hi; i += 256) {
    uint u = binned[i];
    int key = (int)((u >> 17) << 3) | (int)((u & 0x1FFFFu) >> 14);
    atomicAdd(&h[key], 1);
  }
  __syncthreads();
  // exclusive scan over 4096 entries: 16 serial per thread + block scan
  const int b16 = tid * 16;
  int loc[16];
  int s = 0;
#pragma unroll
  for (int j = 0; j < 16; ++j) {
    loc[j] = s;
    s += h[b16 + j];
  }
  ps[tid] = s;
  __syncthreads();
  for (int o = 1; o < 256; o <<= 1) {
    int t = 0;
    if (tid >= o) t = ps[tid - o];
    __syncthreads();
    ps[tid] += t;
    __syncthreads();
  }
  const int excl = ps[tid] - s;
#pragma unroll
  for (int j = 0; j < 16; ++j) off[b16 + j] = excl + loc[j];
  __syncthreads();
  const int node0 = b << BUK_SHIFT;
  for (int k = tid; k < BUK_NODES; k += 256) {
    int node = node0 + k;
    if (node < n) {
      int deg = 0;
#pragma unroll
      for (int c = 0; c < NCH; ++c) deg += h[k * NCH + c];
      dis[node] = rsqrtf((float)(deg + 1));
      int e0 = lo + off[k * NCH];
      int e1 = (k == BUK_NODES - 1) ? hi : lo + off[(k + 1) * NCH];
      ndesc[node] = make_int2(e0, e1);
    }
  }
  __syncthreads();
  for (int i = lo + tid; i < hi; i += 256) {
    uint u = binned[i];
    int key = (int)((u >> 17) << 3) | (int)((u & 0x1FFFFu) >> 14);
    int s2 = (int)(u & 0x1FFFFu);
    int r = atomicAdd(&off[key], 1);
    csr[lo + r] = s2;
  }
}

// ---------------- W preconvert (both layers, one dispatch) ----------------
// Fragment slot (kc,j,lane) holds 8 bf16: W[kc*32 + (lane>>4)*8 + i][j*16 + (lane&15)]

__global__ __launch_bounds__(256) void wconv_kernel(const float* __restrict__ W1,
                                                    const float* __restrict__ W2,
                                                    ushort* __restrict__ Whi1,
                                                    ushort* __restrict__ Wlo1,
                                                    ushort* __restrict__ Whi2,
                                                    ushort* __restrict__ Wlo2) {
  const int g = blockIdx.x;  // 0..15
  const float* W = (g < 8) ? W1 : W2;
  ushort* Whi = (g < 8) ? Whi1 : Whi2;
  ushort* Wlo = (g < 8) ? Wlo1 : Wlo2;
  int slot = (g & 7) * 256 + threadIdx.x;
  int lane = slot & 63;
  int j = (slot >> 6) & 7;
  int kc = slot >> 9;
  ushort hb[8], lb[8];
#pragma unroll
  for (int i = 0; i < 8; ++i) {
    int k = kc * 32 + ((lane >> 4) << 3) + i;
    int c = j * 16 + (lane & 15);
    float f = W[k * 128 + c];
    uint hi = bf16rne(f);
    float hif = __uint_as_float(hi << 16);
    uint lo = __float_as_uint(f - hif) >> 16;
    hb[i] = (ushort)hi;
    lb[i] = (ushort)lo;
  }
  *reinterpret_cast<uint4*>(Whi + (size_t)slot * 8) = *reinterpret_cast<uint4*>(hb);
  *reinterpret_cast<uint4*>(Wlo + (size_t)slot * 8) = *reinterpret_cast<uint4*>(lb);
}

// ---------------- GEMM via split MFMA ----------------
// ABF16=false: A is f32, bf16x3 split (3 MFMA). ABF16=true: A already bf16 (2 MFMA).

template <bool ABF16>
__global__ __launch_bounds__(256) void gemm_mfma(const void* __restrict__ Ain,
                                                 const ushort* __restrict__ Whi,
                                                 const ushort* __restrict__ Wlo,
                                                 const float* __restrict__ scale,
                                                 uint* __restrict__ Cb, int n) {
  const int tid = threadIdx.x;
  const int wave = tid >> 6, lane = tid & 63;
  const int row = blockIdx.x * 64 + wave * 16 + (lane & 15);
  const int kgrp = lane >> 4;  // 0..3
  const bool rowok = row < n;

  f32x4 acc[8];
#pragma unroll
  for (int j = 0; j < 8; ++j) acc[j] = (f32x4){0.f, 0.f, 0.f, 0.f};

#pragma unroll
  for (int kc = 0; kc < 4; ++kc) {
    short8v ahi, alo;
    if constexpr (ABF16) {
      if (rowok) {
        ahi = *reinterpret_cast<const short8v*>(
            (const ushort*)Ain + (size_t)row * 128 + kc * 32 + kgrp * 8);
      } else {
#pragma unroll
        for (int i = 0; i < 8; ++i) ahi[i] = 0;
      }
    } else {
      const float* ap = (const float*)Ain + (size_t)row * 128 + kc * 32 + kgrp * 8;
      float4 a0 = make_float4(0.f, 0.f, 0.f, 0.f), a1 = a0;
      if (rowok) {
        a0 = *reinterpret_cast<const float4*>(ap);
        a1 = *reinterpret_cast<const float4*>(ap + 4);
      }
#pragma unroll
      for (int i = 0; i < 8; ++i) {
        float f = (i < 4) ? (&a0.x)[i] : (&a1.x)[i - 4];
        uint hi = bf16rne(f);
        float hif = __uint_as_float(hi << 16);
        uint lo = __float_as_uint(f - hif) >> 16;
        ahi[i] = (short)hi;
        alo[i] = (short)lo;
      }
    }
#pragma unroll
    for (int j = 0; j < 8; ++j) {
      const size_t base = ((size_t)(kc * 8 + j) * 64 + lane) * 8;
      short8v whi = *reinterpret_cast<const short8v*>(Whi + base);
      short8v wlo = *reinterpret_cast<const short8v*>(Wlo + base);
      acc[j] = __builtin_amdgcn_mfma_f32_16x16x32_bf16(whi, ahi, acc[j], 0, 0, 0);
      if constexpr (!ABF16)
        acc[j] = __builtin_amdgcn_mfma_f32_16x16x32_bf16(whi, alo, acc[j], 0, 0, 0);
      acc[j] = __builtin_amdgcn_mfma_f32_16x16x32_bf16(wlo, ahi, acc[j], 0, 0, 0);
    }
  }

  if (rowok) {
    const float s = scale[row];
#pragma unroll
    for (int j = 0; j < 8; ++j) {
      uint u0 = bf16rne(acc[j][0] * s) | (bf16rne(acc[j][1] * s) << 16);
      uint u1 = bf16rne(acc[j][2] * s) | (bf16rne(acc[j][3] * s) << 16);
      *reinterpret_cast<uint2*>(Cb + (size_t)row * 64 + j * 8 + kgrp * 2) =
          make_uint2(u0, u1);
    }
  }
}

// ---------------- aggregation ----------------
// O[i] = bf16( relu( dis[i]*( sum_{e} T'[src] + T'[i] ) + b ) )
// 4 edges per gather instruction: lane = 16*edgegroup + featsub; each lane loads
// uint4 (8 features) of its group's edge row; cross-group shfl_xor reduce at end.

__global__ __launch_bounds__(256) void agg_kernel(const uint* __restrict__ T,
                                                  const int2* __restrict__ ndesc,
                                                  const int* __restrict__ csr,
                                                  const float* __restrict__ dis,
                                                  const float* __restrict__ bias,
                                                  uint* __restrict__ O, int n) {
  int wid = (blockIdx.x << 2) + (threadIdx.x >> 6);  // one wave per node
  if (wid >= n) return;
  wid = __builtin_amdgcn_readfirstlane(wid);
  const int lane = threadIdx.x & 63;
  const int sub = lane & 15;  // feature sub-block: features sub*8 .. sub*8+7
  const int grp = lane >> 4;  // edge group 0..3
  const uint4* T4 = reinterpret_cast<const uint4*>(T) + sub;  // row r at r*16
  const int2 dd = ndesc[wid];
  const float di = dis[wid];

  float acc[8];
#pragma unroll
  for (int j = 0; j < 8; ++j) acc[j] = 0.f;

#define ACC8(g)                          \
  do {                                   \
    acc[0] += blo((g).x);                \
    acc[1] += bhi((g).x);                \
    acc[2] += blo((g).y);                \
    acc[3] += bhi((g).y);                \
    acc[4] += blo((g).z);                \
    acc[5] += bhi((g).z);                \
    acc[6] += blo((g).w);                \
    acc[7] += bhi((g).w);                \
  } while (0)

  for (int base = dd.x; base < dd.y; base += 64) {
    const int cn = min(64, dd.y - base);                // uniform
    const int sv = (lane < cn) ? csr[base + lane] : 0;  // coalesced
    int e = 0;
    for (; e + 16 <= cn; e += 16) {  // 16 edges via 4 gather instrs, all in flight
      int s0 = __shfl(sv, e + grp, 64);
      int s1 = __shfl(sv, e + 4 + grp, 64);
      int s2 = __shfl(sv, e + 8 + grp, 64);
      int s3 = __shfl(sv, e + 12 + grp, 64);
      uint4 g0 = T4[(size_t)s0 * 16];
      uint4 g1 = T4[(size_t)s1 * 16];
      uint4 g2 = T4[(size_t)s2 * 16];
      uint4 g3 = T4[(size_t)s3 * 16];
      ACC8(g0);
      ACC8(g1);
      ACC8(g2);
      ACC8(g3);
    }
    for (; e < cn; e += 4) {  // tail: 4 edges per instr, predicated
      int ei = e + grp;
      int s = __shfl(sv, (ei < cn) ? ei : 0, 64);
      uint4 g = T4[(size_t)s * 16];
      if (ei < cn) ACC8(g);
    }
  }
  // reduce across the 4 edge groups (lanes l, l^16, l^32, l^48)
#pragma unroll
  for (int j = 0; j < 8; ++j) {
    acc[j] += __shfl_xor(acc[j], 16, 64);
    acc[j] += __shfl_xor(acc[j], 32, 64);
  }
  // self loop + bias + relu + pack (groups redundant; grp 0 stores)
  uint4 us = T4[(size_t)wid * 16];
  float4 b0 = *reinterpret_cast<const float4*>(bias + sub * 8);
  float4 b1 = *reinterpret_cast<const float4*>(bias + sub * 8 + 4);
  float o0 = fmaxf(fmaf(di, acc[0] + blo(us.x), b0.x), 0.f);
  float o1 = fmaxf(fmaf(di, acc[1] + bhi(us.x), b0.y), 0.f);
  float o2 = fmaxf(fmaf(di, acc[2] + blo(us.y), b0.z), 0.f);
  float o3 = fmaxf(fmaf(di, acc[3] + bhi(us.y), b0.w), 0.f);
  float o4 = fmaxf(fmaf(di, acc[4] + blo(us.z), b1.x), 0.f);
  float o5 = fmaxf(fmaf(di, acc[5] + bhi(us.z), b1.y), 0.f);
  float o6 = fmaxf(fmaf(di, acc[6] + blo(us.w), b1.z), 0.f);
  float o7 = fmaxf(fmaf(di, acc[7] + bhi(us.w), b1.w), 0.f);
  if (grp == 0) {
    uint4 ov;
    ov.x = bf16rne(o0) | (bf16rne(o1) << 16);
    ov.y = bf16rne(o2) | (bf16rne(o3) << 16);
    ov.z = bf16rne(o4) | (bf16rne(o5) << 16);
    ov.w = bf16rne(o6) | (bf16rne(o7) << 16);
    reinterpret_cast<uint4*>(O)[(size_t)wid * 16 + sub] = ov;
  }
#undef ACC8
}

// ---------------- pooling over sorted batch ids (bf16 input) ----------------

__global__ __launch_bounds__(256) void pool_kernel(const uint* __restrict__ H,
                                                   const int* __restrict__ batch,
                                                   float* __restrict__ pooled,
                                                   float* __restrict__ cntg, int n) {
  __shared__ float sd[256 * 4];
  const int tid = threadIdx.x;
  const int c4 = (tid & 31) << 2;  // column base (4 cols = 2 uints)
  const int rs = tid >> 5;         // 0..7 row subgroup
  const int base = blockIdx.x * PCHUNK;
  const int lim = min(base + PCHUNK, n);
  const int g0 = batch[base];
  const int gN = batch[lim - 1];
  float4 acc = make_float4(0.f, 0.f, 0.f, 0.f);
  if (g0 == gN) {
    for (int r = base + rs; r < lim; r += 8) {
      uint2 v = *reinterpret_cast<const uint2*>(H + (size_t)r * 64 + (c4 >> 1));
      acc.x += blo(v.x); acc.y += bhi(v.x); acc.z += blo(v.y); acc.w += bhi(v.y);
    }
    *reinterpret_cast<float4*>(&sd[tid * 4]) = acc;
    __syncthreads();
    if (tid < 128) {
      float4 o = *reinterpret_cast<float4*>(&sd[(tid + 128) * 4]);
      acc.x += o.x; acc.y += o.y; acc.z += o.z; acc.w += o.w;
      *reinterpret_cast<float4*>(&sd[tid * 4]) = acc;
    }
    __syncthreads();
    if (tid < 64) {
      float4 o = *reinterpret_cast<float4*>(&sd[(tid + 64) * 4]);
      acc.x += o.x; acc.y += o.y; acc.z += o.z; acc.w += o.w;
      *reinterpret_cast<float4*>(&sd[tid * 4]) = acc;
    }
    __syncthreads();
    if (tid < 32) {
      float4 o = *reinterpret_cast<float4*>(&sd[(tid + 32) * 4]);
      acc.x += o.x; acc.y += o.y; acc.z += o.z; acc.w += o.w;
      atomicAdd(&pooled[g0 * 128 + c4 + 0], acc.x);
      atomicAdd(&pooled[g0 * 128 + c4 + 1], acc.y);
      atomicAdd(&pooled[g0 * 128 + c4 + 2], acc.z);
      atomicAdd(&pooled[g0 * 128 + c4 + 3], acc.w);
      if (tid == 0) atomicAdd(&cntg[g0], (float)(lim - base));
    }
  } else {
    int curg = -1, cnt = 0;
    for (int r = base + rs; r < lim; r += 8) {
      int g = batch[r];
      if (g != curg) {
        if (curg >= 0) {
          atomicAdd(&pooled[curg * 128 + c4 + 0], acc.x);
          atomicAdd(&pooled[curg * 128 + c4 + 1], acc.y);
          atomicAdd(&pooled[curg * 128 + c4 + 2], acc.z);
          atomicAdd(&pooled[curg * 128 + c4 + 3], acc.w);
          if ((tid & 31) == 0) atomicAdd(&cntg[curg], (float)cnt);
        }
        curg = g;
        acc = make_float4(0.f, 0.f, 0.f, 0.f);
        cnt = 0;
      }
      uint2 v = *reinterpret_cast<const uint2*>(H + (size_t)r * 64 + (c4 >> 1));
      acc.x += blo(v.x); acc.y += bhi(v.x); acc.z += blo(v.y); acc.w += bhi(v.y);
      cnt++;
    }
    if (curg >= 0) {
      atomicAdd(&pooled[curg * 128 + c4 + 0], acc.x);
      atomicAdd(&pooled[curg * 128 + c4 + 1], acc.y);
      atomicAdd(&pooled[curg * 128 + c4 + 2], acc.z);
      atomicAdd(&pooled[curg * 128 + c4 + 3], acc.w);
      if ((tid & 31) == 0) atomicAdd(&cntg[curg], (float)cnt);
    }
  }
}

__global__ __launch_bounds__(128) void final_kernel(const float* __restrict__ pooled,
                                                    const float* __restrict__ cntg,
                                                    const float* __restrict__ Wp,
                                                    const float* __restrict__ bp,
                                                    float* __restrict__ out) {
  const int g = blockIdx.x;
  const int e = threadIdx.x;
  float inv = 1.0f / fmaxf(cntg[g], 1.0f);
  float acc = 0.f;
  for (int c = 0; c < 128; ++c)
    acc = fmaf(pooled[g * 128 + c], Wp[c * 128 + e], acc);
  out[g * 128 + e] = acc * inv + bp[e];
}

// ---------------- launch ----------------

extern "C" void kernel_launch(void* const* d_in, const int* in_sizes, int n_in,
                              void* d_out, int out_size, void* d_ws, size_t ws_size,
                              hipStream_t stream) {
  const float* x = (const float*)d_in[0];
  const int* eidx = (const int*)d_in[1];
  const int* batch = (const int*)d_in[2];
  const float* W1 = (const float*)d_in[3];
  const float* b1 = (const float*)d_in[4];
  const float* W2 = (const float*)d_in[5];
  const float* b2 = (const float*)d_in[6];
  const float* Wp = (const float*)d_in[7];
  const float* bp = (const float*)d_in[8];

  const int n = in_sizes[0] / 128;
  const int E = in_sizes[1] / 2;
  const int* row = eidx;      // edge_index[0] = sources
  const int* col = eidx + E;  // edge_index[1] = targets
  const int nbuk = (n + BUK_NODES - 1) >> BUK_SHIFT;

  char* ws = (char*)d_ws;
  size_t off = 0;
  auto alloc = [&](size_t bytes) {
    void* p = ws + off;
    off = (off + bytes + 255) & ~(size_t)255;
    return p;
  };
  uint* Tb = (uint*)alloc((size_t)n * 64 * 4);   // bf16-packed messages
  uint* Bb = (uint*)alloc((size_t)n * 64 * 4);   // bf16-packed hidden state
  float* dis = (float*)alloc((size_t)n * 4);
  int2* ndesc = (int2*)alloc((size_t)n * 8);
  int* csr = (int*)alloc((size_t)nbuk * BCAP * 4);
  uint* binned = (uint*)alloc((size_t)nbuk * BCAP * 4);
  int* gcur = (int*)alloc(256 * 4);
  // contiguous zero region: cntg(64) | pooled(GG*128)
  float* zbase = (float*)alloc((64 + GG * 128) * 4);
  float* cntg = zbase;
  float* pooled = zbase + 64;
  ushort* Whi1 = (ushort*)alloc(2048 * 8 * 2);
  ushort* Wlo1 = (ushort*)alloc(2048 * 8 * 2);
  ushort* Whi2 = (ushort*)alloc(2048 * 8 * 2);
  ushort* Wlo2 = (ushort*)alloc(2048 * 8 * 2);
  (void)off;

  hipMemsetAsync(zbase, 0, (64 + GG * 128) * 4, stream);
  initcur_kernel<<<1, 256, 0, stream>>>(gcur);

  const int eblocks = (E + EPB - 1) / EPB;
  bin_kernel<<<eblocks, 256, 0, stream>>>(row, col, gcur, binned, E);
  build_kernel<<<nbuk, 256, 0, stream>>>(binned, gcur, ndesc, dis, csr, n);
  wconv_kernel<<<16, 256, 0, stream>>>(W1, W2, Whi1, Wlo1, Whi2, Wlo2);

  const int gblocks = (n + 63) / 64;
  gemm_mfma<false><<<gblocks, 256, 0, stream>>>(x, Whi1, Wlo1, dis, Tb, n);
  agg_kernel<<<(n + 3) / 4, 256, 0, stream>>>(Tb, ndesc, csr, dis, b1, Bb, n);
  gemm_mfma<true><<<gblocks, 256, 0, stream>>>(Bb, Whi2, Wlo2, dis, Tb, n);
  agg_kernel<<<(n + 3) / 4, 256, 0, stream>>>(Tb, ndesc, csr, dis, b2, Bb, n);

  pool_kernel<<<(n + PCHUNK - 1) / PCHUNK, 256, 0, stream>>>(Bb, batch, pooled, cntg, n);
  final_kernel<<<GG, 128, 0, stream>>>(pooled, cntg, Wp, bp, (float*)d_out);
}